// Round 1
// baseline (1666.638 us; speedup 1.0000x reference)
//
#include <hip/hip_runtime.h>
#include <hip/hip_bf16.h>

#define N_NODES 50000
#define N_EDGES 800000
#define HID 128
#define NUM_GRAPHS 64

typedef __attribute__((ext_vector_type(8))) short short8;
typedef __attribute__((ext_vector_type(4))) float f32x4;

static __device__ __forceinline__ short f2bf(float f) {
    union { __hip_bfloat16 h; short s; } u;
    u.h = __float2bfloat16(f);
    return u.s;
}

// Fold: Wcat[o][0:128] = Wu[o][0:128];  Wcat[o][128+k] = sum_j Wu[o][128+j]*Wm[j][k]
//       cvec[o] = sum_j Wu[o][128+j]*bm[j]
__global__ void fold_kernel(const float* __restrict__ Wu, const float* __restrict__ Wm,
                            const float* __restrict__ bm, short* __restrict__ Wcat,
                            float* __restrict__ cvec) {
    int o = blockIdx.x;   // 0..127
    int k = threadIdx.x;  // 0..127
    float s = 0.f;
    for (int j = 0; j < 128; ++j) s += Wu[o * 256 + 128 + j] * Wm[j * 128 + k];
    Wcat[o * 256 + 128 + k] = f2bf(s);
    Wcat[o * 256 + k] = f2bf(Wu[o * 256 + k]);
    if (k == 0) {
        float cs = 0.f;
        for (int j = 0; j < 128; ++j) cs += Wu[o * 256 + 128 + j] * bm[j];
        cvec[o] = cs;
    }
}

__global__ void deg_kernel(const int* __restrict__ row, float* __restrict__ deg, int E) {
    int e = blockIdx.x * 256 + threadIdx.x;
    if (e < E) atomicAdd(&deg[row[e]], 1.0f);
}

__global__ void cnt_kernel(const int* __restrict__ batch, float* __restrict__ cnt, int N) {
    __shared__ float loc[NUM_GRAPHS];
    int t = threadIdx.x;
    if (t < NUM_GRAPHS) loc[t] = 0.f;
    __syncthreads();
    int n = blockIdx.x * 256 + t;
    if (n < N) atomicAdd(&loc[batch[n]], 1.0f);
    __syncthreads();
    if (t < NUM_GRAPHS && loc[t] != 0.f) atomicAdd(&cnt[t], loc[t]);
}

// agg[row[e]] += src[col[e]]  (128 channels, one edge per wave-iteration)
__global__ __launch_bounds__(256) void scatter_kernel(const float* __restrict__ src,
                                                      const int* __restrict__ row,
                                                      const int* __restrict__ col,
                                                      float* __restrict__ agg, int E) {
    int wave = threadIdx.x >> 6, lane = threadIdx.x & 63;
    int e0 = (blockIdx.x * 4 + wave) * 8;
#pragma unroll
    for (int i = 0; i < 8; ++i) {
        int e = e0 + i;
        if (e >= E) break;
        int r = row[e], c = col[e];
        float2 v = *(const float2*)(src + (size_t)c * 128 + lane * 2);
        atomicAdd(&agg[(size_t)r * 128 + lane * 2], v.x);
        atomicAdd(&agg[(size_t)r * 128 + lane * 2 + 1], v.y);
    }
}

// h = relu(xin @ Wcat[:, :128]^T + agg @ Wcat[:, 128:]^T + deg*c + bu)
// Block: 256 thr = 4 waves; block tile = 64 nodes x 128 outs; wave = 16 nodes x 128 outs.
__global__ __launch_bounds__(256) void update_kernel(
    const float* __restrict__ xin, const float* __restrict__ agg,
    const float* __restrict__ deg, const float* __restrict__ cvec,
    const float* __restrict__ bupd, const short* __restrict__ Wcat,
    float* __restrict__ hout, float* __restrict__ pooled,
    const int* __restrict__ batch, int N, int pool) {
    int wave = threadIdx.x >> 6, lane = threadIdx.x & 63;
    int node0 = blockIdx.x * 64 + wave * 16;
    int lrow = lane & 15, lk = lane >> 4;
    int nr = node0 + lrow;
    if (nr > N - 1) nr = N - 1;
    f32x4 acc[8] = {};
#pragma unroll
    for (int s = 0; s < 8; ++s) {
        const float* srcp = (s < 4) ? (xin + (size_t)nr * 128 + s * 32 + lk * 8)
                                    : (agg + (size_t)nr * 128 + (s - 4) * 32 + lk * 8);
        float4 f0 = *(const float4*)srcp;
        float4 f1 = *(const float4*)(srcp + 4);
        short8 a;
        a[0] = f2bf(f0.x); a[1] = f2bf(f0.y); a[2] = f2bf(f0.z); a[3] = f2bf(f0.w);
        a[4] = f2bf(f1.x); a[5] = f2bf(f1.y); a[6] = f2bf(f1.z); a[7] = f2bf(f1.w);
#pragma unroll
        for (int t = 0; t < 8; ++t) {
            short8 b = *(const short8*)(Wcat + (size_t)(lrow + 16 * t) * 256 + s * 32 + lk * 8);
            acc[t] = __builtin_amdgcn_mfma_f32_16x16x32_bf16(a, b, acc[t], 0, 0, 0);
        }
    }
#pragma unroll
    for (int t = 0; t < 8; ++t) {
        int o = lrow + 16 * t;
        float co = cvec[o], bo = bupd[o];
#pragma unroll
        for (int r = 0; r < 4; ++r) {
            int node = node0 + lk * 4 + r;
            if (node < N) {
                float v = fmaxf(acc[t][r] + deg[node] * co + bo, 0.0f);
                if (pool)
                    atomicAdd(&pooled[(size_t)batch[node] * 128 + o], v);
                else
                    hout[(size_t)node * 128 + o] = v;
            }
        }
    }
}

__global__ void final_kernel(const float* __restrict__ pooled, const float* __restrict__ cnt,
                             const float* __restrict__ Wcls, const float* __restrict__ bcls,
                             float* __restrict__ out) {
    __shared__ float sh[128];
    int g = blockIdx.x;
    int t = threadIdx.x;
    sh[t] = pooled[g * 128 + t] / cnt[g];
    __syncthreads();
    if (t < 10) {
        float s = bcls[t];
        for (int i = 0; i < 128; ++i) s += sh[i] * Wcls[t * 128 + i];
        out[g * 10 + t] = s;
    }
}

extern "C" void kernel_launch(void* const* d_in, const int* in_sizes, int n_in,
                              void* d_out, int out_size, void* d_ws, size_t ws_size,
                              hipStream_t stream) {
    const float* x = (const float*)d_in[0];
    const int* ei = (const int*)d_in[1];
    const int* batch = (const int*)d_in[2];
    const float* Wm1 = (const float*)d_in[3];
    const float* bm1 = (const float*)d_in[4];
    const float* Wu1 = (const float*)d_in[5];
    const float* bu1 = (const float*)d_in[6];
    const float* Wm2 = (const float*)d_in[7];
    const float* bm2 = (const float*)d_in[8];
    const float* Wu2 = (const float*)d_in[9];
    const float* bu2 = (const float*)d_in[10];
    const float* Wcls = (const float*)d_in[11];
    const float* bcls = (const float*)d_in[12];
    float* out = (float*)d_out;

    const int N = N_NODES, E = N_EDGES;
    const int* row = ei;
    const int* col = ei + E;

    float* ws = (float*)d_ws;
    float* agg = ws;                     // 6,400,000 floats
    float* deg = ws + 6400000;           // 50,000
    float* pooled = ws + 6450000;        // 8,192
    float* cnt = ws + 6458192;           // 64
    float* h1 = ws + 6458256;            // 6,400,000
    float* c1 = ws + 12858256;           // 128
    float* c2 = ws + 12858384;           // 128
    short* Wcat1 = (short*)(ws + 12858512);  // 32768 shorts
    short* Wcat2 = Wcat1 + 32768;            // 32768 shorts

    // zero agg + deg + pooled + cnt (contiguous region)
    hipMemsetAsync(ws, 0, (size_t)6458256 * sizeof(float), stream);

    fold_kernel<<<128, 128, 0, stream>>>(Wu1, Wm1, bm1, Wcat1, c1);
    fold_kernel<<<128, 128, 0, stream>>>(Wu2, Wm2, bm2, Wcat2, c2);
    deg_kernel<<<(E + 255) / 256, 256, 0, stream>>>(row, deg, E);
    cnt_kernel<<<(N + 255) / 256, 256, 0, stream>>>(batch, cnt, N);

    // layer 1
    scatter_kernel<<<E / 32, 256, 0, stream>>>(x, row, col, agg, E);
    update_kernel<<<(N + 63) / 64, 256, 0, stream>>>(x, agg, deg, c1, bu1, Wcat1,
                                                     h1, nullptr, nullptr, N, 0);
    // layer 2
    hipMemsetAsync(agg, 0, (size_t)6400000 * sizeof(float), stream);
    scatter_kernel<<<E / 32, 256, 0, stream>>>(h1, row, col, agg, E);
    update_kernel<<<(N + 63) / 64, 256, 0, stream>>>(h1, agg, deg, c2, bu2, Wcat2,
                                                     nullptr, pooled, batch, N, 1);

    final_kernel<<<NUM_GRAPHS, 128, 0, stream>>>(pooled, cnt, Wcls, bcls, out);
}

// Round 2
// 453.089 us; speedup vs baseline: 3.6784x; 3.6784x over previous
//
#include <hip/hip_runtime.h>
#include <hip/hip_bf16.h>

#define N_NODES 50000
#define N_EDGES 800000
#define HID 128
#define NUM_GRAPHS 64

typedef __attribute__((ext_vector_type(8))) short short8;
typedef __attribute__((ext_vector_type(4))) float f32x4;

static __device__ __forceinline__ short f2bf(float f) {
    union { __hip_bfloat16 h; short s; } u;
    u.h = __float2bfloat16(f);
    return u.s;
}
static __device__ __forceinline__ unsigned short f2bfu(float f) {
    union { __hip_bfloat16 h; unsigned short s; } u;
    u.h = __float2bfloat16(f);
    return u.s;
}

// Fold: Wcat[o][0:128] = Wu[o][0:128];  Wcat[o][128+k] = sum_j Wu[o][128+j]*Wm[j][k]
//       cvec[o] = sum_j Wu[o][128+j]*bm[j]
__global__ void fold_kernel(const float* __restrict__ Wu, const float* __restrict__ Wm,
                            const float* __restrict__ bm, short* __restrict__ Wcat,
                            float* __restrict__ cvec) {
    int o = blockIdx.x;   // 0..127
    int k = threadIdx.x;  // 0..127
    float s = 0.f;
    for (int j = 0; j < 128; ++j) s += Wu[o * 256 + 128 + j] * Wm[j * 128 + k];
    Wcat[o * 256 + 128 + k] = f2bf(s);
    Wcat[o * 256 + k] = f2bf(Wu[o * 256 + k]);
    if (k == 0) {
        float cs = 0.f;
        for (int j = 0; j < 128; ++j) cs += Wu[o * 256 + 128 + j] * bm[j];
        cvec[o] = cs;
    }
}

__global__ void hist_kernel(const int* __restrict__ row, int* __restrict__ hist, int E) {
    int e = blockIdx.x * 256 + threadIdx.x;
    if (e < E) atomicAdd(&hist[row[e]], 1);
}

__global__ void cnt_kernel(const int* __restrict__ batch, float* __restrict__ cnt, int N) {
    __shared__ float loc[NUM_GRAPHS];
    int t = threadIdx.x;
    if (t < NUM_GRAPHS) loc[t] = 0.f;
    __syncthreads();
    int n = blockIdx.x * 256 + t;
    if (n < N) atomicAdd(&loc[batch[n]], 1.0f);
    __syncthreads();
    if (t < NUM_GRAPHS && loc[t] != 0.f) atomicAdd(&cnt[t], loc[t]);
}

// ---- 3-kernel exclusive scan over hist[N] -> off[N], block sums in bsum ----
__global__ void scanA_kernel(const int* __restrict__ hist, int* __restrict__ off,
                             int* __restrict__ bsum, int N) {
    __shared__ int sh[256];
    int t = threadIdx.x, idx = blockIdx.x * 256 + t;
    int v = (idx < N) ? hist[idx] : 0;
    sh[t] = v;
    __syncthreads();
    for (int o = 1; o < 256; o <<= 1) {
        int a = (t >= o) ? sh[t - o] : 0;
        __syncthreads();
        sh[t] += a;
        __syncthreads();
    }
    if (idx < N) off[idx] = sh[t] - v;
    if (t == 255) bsum[blockIdx.x] = sh[255];
}

__global__ void scanB_kernel(int* __restrict__ bsum, int nb) {
    __shared__ int sh[256];
    int t = threadIdx.x;
    int v = (t < nb) ? bsum[t] : 0;
    sh[t] = v;
    __syncthreads();
    for (int o = 1; o < 256; o <<= 1) {
        int a = (t >= o) ? sh[t - o] : 0;
        __syncthreads();
        sh[t] += a;
        __syncthreads();
    }
    if (t < nb) bsum[t] = sh[t] - v;  // exclusive
}

__global__ void scanC_kernel(int* __restrict__ off, const int* __restrict__ bsum, int N) {
    int idx = blockIdx.x * 256 + threadIdx.x;
    if (idx < N) off[idx] += bsum[blockIdx.x];
}

__global__ void place_kernel(const int* __restrict__ row, const int* __restrict__ col,
                             const int* __restrict__ off, int* __restrict__ cursor,
                             int* __restrict__ csr, int E) {
    int e = blockIdx.x * 256 + threadIdx.x;
    if (e < E) {
        int r = row[e];
        int pos = off[r] + atomicAdd(&cursor[r], 1);
        csr[pos] = col[e];
    }
}

// agg[n] = sum over csr neighbors of src rows. One wave per node; lane owns 2 channels.
// BF16=0: src is fp32 [N][128]; BF16=1: src is bf16 pairs [N][64] uints. Output bf16 pairs.
template <int BF16>
__global__ __launch_bounds__(256) void gather_kernel(const void* __restrict__ src_,
                                                     const int* __restrict__ off,
                                                     const int* __restrict__ hist,
                                                     const int* __restrict__ csr,
                                                     unsigned int* __restrict__ aggb, int N) {
    int wave = threadIdx.x >> 6, lane = threadIdx.x & 63;
    int n = blockIdx.x * 4 + wave;
    if (n >= N) return;
    int s = off[n];
    int e = s + hist[n];
    float a0 = 0.f, a1 = 0.f;
    for (int base = s; base < e; base += 64) {
        int m = e - base;
        if (m > 64) m = 64;
        int ce = (base + lane < e) ? csr[base + lane] : 0;
        int i = 0;
        for (; i + 4 <= m; i += 4) {
            int c0 = __shfl(ce, i), c1 = __shfl(ce, i + 1);
            int c2 = __shfl(ce, i + 2), c3 = __shfl(ce, i + 3);
            if (BF16) {
                const unsigned int* p = (const unsigned int*)src_;
                unsigned v0 = p[(size_t)c0 * 64 + lane];
                unsigned v1 = p[(size_t)c1 * 64 + lane];
                unsigned v2 = p[(size_t)c2 * 64 + lane];
                unsigned v3 = p[(size_t)c3 * 64 + lane];
                a0 += __uint_as_float(v0 << 16) + __uint_as_float(v1 << 16) +
                      __uint_as_float(v2 << 16) + __uint_as_float(v3 << 16);
                a1 += __uint_as_float(v0 & 0xffff0000u) + __uint_as_float(v1 & 0xffff0000u) +
                      __uint_as_float(v2 & 0xffff0000u) + __uint_as_float(v3 & 0xffff0000u);
            } else {
                const float2* p = (const float2*)src_;
                float2 v0 = p[(size_t)c0 * 64 + lane];
                float2 v1 = p[(size_t)c1 * 64 + lane];
                float2 v2 = p[(size_t)c2 * 64 + lane];
                float2 v3 = p[(size_t)c3 * 64 + lane];
                a0 += v0.x + v1.x + v2.x + v3.x;
                a1 += v0.y + v1.y + v2.y + v3.y;
            }
        }
        for (; i < m; ++i) {
            int c = __shfl(ce, i);
            if (BF16) {
                unsigned v = ((const unsigned int*)src_)[(size_t)c * 64 + lane];
                a0 += __uint_as_float(v << 16);
                a1 += __uint_as_float(v & 0xffff0000u);
            } else {
                float2 v = ((const float2*)src_)[(size_t)c * 64 + lane];
                a0 += v.x;
                a1 += v.y;
            }
        }
    }
    unsigned r = ((unsigned)f2bfu(a1) << 16) | (unsigned)f2bfu(a0);
    aggb[(size_t)n * 64 + lane] = r;
}

// h = relu([xin | agg] @ Wcat^T + deg*c + bu); agg is bf16, xin fp32 or bf16.
// Block: 256 thr = 4 waves; block tile = 64 nodes x 128 outs.
template <int XIN_BF16, int POOL>
__global__ __launch_bounds__(256) void update_kernel(
    const void* __restrict__ xin_, const short* __restrict__ aggb,
    const int* __restrict__ hist, const float* __restrict__ cvec,
    const float* __restrict__ bupd, const short* __restrict__ Wcat,
    unsigned short* __restrict__ houtb, float* __restrict__ pooled,
    const int* __restrict__ batch, int N) {
    int wave = threadIdx.x >> 6, lane = threadIdx.x & 63;
    int node0 = blockIdx.x * 64 + wave * 16;
    int lrow = lane & 15, lk = lane >> 4;
    int nr = node0 + lrow;
    if (nr > N - 1) nr = N - 1;
    f32x4 acc[8] = {};
#pragma unroll
    for (int s = 0; s < 8; ++s) {
        short8 a;
        if (s < 4) {
            if (XIN_BF16) {
                a = *(const short8*)((const short*)xin_ + (size_t)nr * 128 + s * 32 + lk * 8);
            } else {
                const float* srcp = (const float*)xin_ + (size_t)nr * 128 + s * 32 + lk * 8;
                float4 f0 = *(const float4*)srcp;
                float4 f1 = *(const float4*)(srcp + 4);
                a[0] = f2bf(f0.x); a[1] = f2bf(f0.y); a[2] = f2bf(f0.z); a[3] = f2bf(f0.w);
                a[4] = f2bf(f1.x); a[5] = f2bf(f1.y); a[6] = f2bf(f1.z); a[7] = f2bf(f1.w);
            }
        } else {
            a = *(const short8*)(aggb + (size_t)nr * 128 + (s - 4) * 32 + lk * 8);
        }
#pragma unroll
        for (int t = 0; t < 8; ++t) {
            short8 b = *(const short8*)(Wcat + (size_t)(lrow + 16 * t) * 256 + s * 32 + lk * 8);
            acc[t] = __builtin_amdgcn_mfma_f32_16x16x32_bf16(a, b, acc[t], 0, 0, 0);
        }
    }
#pragma unroll
    for (int t = 0; t < 8; ++t) {
        int o = lrow + 16 * t;
        float co = cvec[o], bo = bupd[o];
#pragma unroll
        for (int r = 0; r < 4; ++r) {
            int node = node0 + lk * 4 + r;
            if (node < N) {
                float v = fmaxf(acc[t][r] + (float)hist[node] * co + bo, 0.0f);
                if (POOL)
                    atomicAdd(&pooled[(size_t)batch[node] * 128 + o], v);
                else
                    houtb[(size_t)node * 128 + o] = f2bfu(v);
            }
        }
    }
}

__global__ void final_kernel(const float* __restrict__ pooled, const float* __restrict__ cnt,
                             const float* __restrict__ Wcls, const float* __restrict__ bcls,
                             float* __restrict__ out) {
    __shared__ float sh[128];
    int g = blockIdx.x;
    int t = threadIdx.x;
    sh[t] = pooled[g * 128 + t] / cnt[g];
    __syncthreads();
    if (t < 10) {
        float s = bcls[t];
        for (int i = 0; i < 128; ++i) s += sh[i] * Wcls[t * 128 + i];
        out[g * 10 + t] = s;
    }
}

extern "C" void kernel_launch(void* const* d_in, const int* in_sizes, int n_in,
                              void* d_out, int out_size, void* d_ws, size_t ws_size,
                              hipStream_t stream) {
    const float* x = (const float*)d_in[0];
    const int* ei = (const int*)d_in[1];
    const int* batch = (const int*)d_in[2];
    const float* Wm1 = (const float*)d_in[3];
    const float* bm1 = (const float*)d_in[4];
    const float* Wu1 = (const float*)d_in[5];
    const float* bu1 = (const float*)d_in[6];
    const float* Wm2 = (const float*)d_in[7];
    const float* bm2 = (const float*)d_in[8];
    const float* Wu2 = (const float*)d_in[9];
    const float* bu2 = (const float*)d_in[10];
    const float* Wcls = (const float*)d_in[11];
    const float* bcls = (const float*)d_in[12];
    float* out = (float*)d_out;

    const int N = N_NODES, E = N_EDGES;
    const int* row = ei;
    const int* col = ei + E;
    const int NB = (N + 255) / 256;  // 196 scan blocks

    // workspace layout
    int* hist = (int*)d_ws;                     // 50000
    int* cursor = hist + 50000;                 // 50000
    float* pooled = (float*)(cursor + 50000);   // 8192
    float* cnt = pooled + 8192;                 // 64
    int* off = (int*)(cnt + 64);                // 50000
    int* bsum = off + 50000;                    // 256
    int* csr = bsum + 256;                      // 800000
    unsigned int* aggb = (unsigned int*)(csr + 800000);  // 3,200,000 (bf16 pairs)
    unsigned int* h1b = aggb + 3200000;                  // 3,200,000
    float* c1 = (float*)(h1b + 3200000);        // 128
    float* c2 = c1 + 128;                       // 128
    short* Wcat1 = (short*)(c2 + 128);          // 32768
    short* Wcat2 = Wcat1 + 32768;               // 32768

    // zero hist + cursor + pooled + cnt (contiguous)
    hipMemsetAsync(d_ws, 0, (size_t)(50000 + 50000 + 8192 + 64) * 4, stream);

    fold_kernel<<<128, 128, 0, stream>>>(Wu1, Wm1, bm1, Wcat1, c1);
    fold_kernel<<<128, 128, 0, stream>>>(Wu2, Wm2, bm2, Wcat2, c2);
    cnt_kernel<<<(N + 255) / 256, 256, 0, stream>>>(batch, cnt, N);

    // CSR build (reused by both layers)
    hist_kernel<<<(E + 255) / 256, 256, 0, stream>>>(row, hist, E);
    scanA_kernel<<<NB, 256, 0, stream>>>(hist, off, bsum, N);
    scanB_kernel<<<1, 256, 0, stream>>>(bsum, NB);
    scanC_kernel<<<NB, 256, 0, stream>>>(off, bsum, N);
    place_kernel<<<(E + 255) / 256, 256, 0, stream>>>(row, col, off, cursor, csr, E);

    // layer 1
    gather_kernel<0><<<(N + 3) / 4, 256, 0, stream>>>(x, off, hist, csr, aggb, N);
    update_kernel<0, 0><<<(N + 63) / 64, 256, 0, stream>>>(
        x, (const short*)aggb, hist, c1, bu1, Wcat1, (unsigned short*)h1b, nullptr, nullptr, N);
    // layer 2
    gather_kernel<1><<<(N + 3) / 4, 256, 0, stream>>>(h1b, off, hist, csr, aggb, N);
    update_kernel<1, 1><<<(N + 63) / 64, 256, 0, stream>>>(
        h1b, (const short*)aggb, hist, c2, bu2, Wcat2, nullptr, pooled, batch, N);

    final_kernel<<<NUM_GRAPHS, 128, 0, stream>>>(pooled, cnt, Wcls, bcls, out);
}

// Round 3
// 233.287 us; speedup vs baseline: 7.1442x; 1.9422x over previous
//
#include <hip/hip_runtime.h>
#include <hip/hip_bf16.h>

#define N_NODES 50000
#define N_EDGES 800000
#define NUM_GRAPHS 64

typedef __attribute__((ext_vector_type(8))) short short8;
typedef __attribute__((ext_vector_type(16))) float f32x16;

static __device__ __forceinline__ short f2bf(float f) {
    union { __hip_bfloat16 h; short s; } u;
    u.h = __float2bfloat16(f);
    return u.s;
}
static __device__ __forceinline__ unsigned short f2bfu(float f) {
    union { __hip_bfloat16 h; unsigned short s; } u;
    u.h = __float2bfloat16(f);
    return u.s;
}

// Wcatf fragment order: frag f = (kblk*128 + o), kblk=k>>3; Wcatf[f*8 + (k&7)] = Wcat[o][k]
// where Wcat[o][0:128]=Wu[o][0:128], Wcat[o][128+j... ] = folded Wu_b @ Wm.
__global__ void fold_kernel(const float* __restrict__ Wu, const float* __restrict__ Wm,
                            const float* __restrict__ bm, short* __restrict__ Wcatf,
                            float* __restrict__ cvec) {
    int o = blockIdx.x;   // 0..127
    int k = threadIdx.x;  // 0..255
    float val;
    if (k < 128) {
        val = Wu[o * 256 + k];
    } else {
        int kk = k - 128;
        float s = 0.f;
        for (int j = 0; j < 128; ++j) s += Wu[o * 256 + 128 + j] * Wm[j * 128 + kk];
        val = s;
    }
    Wcatf[(((k >> 3) * 128) + o) * 8 + (k & 7)] = f2bf(val);
    if (k == 0) {
        float cs = 0.f;
        for (int j = 0; j < 128; ++j) cs += Wu[o * 256 + 128 + j] * bm[j];
        cvec[o] = cs;
    }
}

__global__ void hist_kernel(const int* __restrict__ row, int* __restrict__ hist, int E) {
    int e = blockIdx.x * 256 + threadIdx.x;
    if (e < E) atomicAdd(&hist[row[e]], 1);
}

__global__ void cnt_kernel(const int* __restrict__ batch, float* __restrict__ cnt, int N) {
    __shared__ float loc[NUM_GRAPHS];
    int t = threadIdx.x;
    if (t < NUM_GRAPHS) loc[t] = 0.f;
    __syncthreads();
    int n = blockIdx.x * 256 + t;
    if (n < N) atomicAdd(&loc[batch[n]], 1.0f);
    __syncthreads();
    if (t < NUM_GRAPHS && loc[t] != 0.f) atomicAdd(&cnt[t], loc[t]);
}

__global__ void scanA_kernel(const int* __restrict__ hist, int* __restrict__ off,
                             int* __restrict__ bsum, int N) {
    __shared__ int sh[256];
    int t = threadIdx.x, idx = blockIdx.x * 256 + t;
    int v = (idx < N) ? hist[idx] : 0;
    sh[t] = v;
    __syncthreads();
    for (int o = 1; o < 256; o <<= 1) {
        int a = (t >= o) ? sh[t - o] : 0;
        __syncthreads();
        sh[t] += a;
        __syncthreads();
    }
    if (idx < N) off[idx] = sh[t] - v;
    if (t == 255) bsum[blockIdx.x] = sh[255];
}

__global__ void scanB_kernel(int* __restrict__ bsum, int nb) {
    __shared__ int sh[256];
    int t = threadIdx.x;
    int v = (t < nb) ? bsum[t] : 0;
    sh[t] = v;
    __syncthreads();
    for (int o = 1; o < 256; o <<= 1) {
        int a = (t >= o) ? sh[t - o] : 0;
        __syncthreads();
        sh[t] += a;
        __syncthreads();
    }
    if (t < nb) bsum[t] = sh[t] - v;  // exclusive
}

__global__ void scanC_kernel(int* __restrict__ off, const int* __restrict__ bsum, int N) {
    int idx = blockIdx.x * 256 + threadIdx.x;
    if (idx < N) off[idx] += bsum[blockIdx.x];
}

__global__ void place_kernel(const int* __restrict__ row, const int* __restrict__ col,
                             const int* __restrict__ off, int* __restrict__ cursor,
                             int* __restrict__ csr, int E) {
    int e = blockIdx.x * 256 + threadIdx.x;
    if (e < E) {
        int r = row[e];
        int pos = off[r] + atomicAdd(&cursor[r], 1);
        csr[pos] = col[e];
    }
}

// agg[n] = sum over csr neighbors of src rows. One wave per node; lane owns 2 channels.
template <int BF16>
__global__ __launch_bounds__(256) void gather_kernel(const void* __restrict__ src_,
                                                     const int* __restrict__ off,
                                                     const int* __restrict__ hist,
                                                     const int* __restrict__ csr,
                                                     unsigned int* __restrict__ aggb, int N) {
    int wave = threadIdx.x >> 6, lane = threadIdx.x & 63;
    int n = blockIdx.x * 4 + wave;
    if (n >= N) return;
    int s = off[n];
    int e = s + hist[n];
    float a0 = 0.f, a1 = 0.f;
    for (int base = s; base < e; base += 64) {
        int m = e - base;
        if (m > 64) m = 64;
        int ce = (base + lane < e) ? csr[base + lane] : 0;
        int i = 0;
        for (; i + 4 <= m; i += 4) {
            int c0 = __shfl(ce, i), c1 = __shfl(ce, i + 1);
            int c2 = __shfl(ce, i + 2), c3 = __shfl(ce, i + 3);
            if (BF16) {
                const unsigned int* p = (const unsigned int*)src_;
                unsigned v0 = p[(size_t)c0 * 64 + lane];
                unsigned v1 = p[(size_t)c1 * 64 + lane];
                unsigned v2 = p[(size_t)c2 * 64 + lane];
                unsigned v3 = p[(size_t)c3 * 64 + lane];
                a0 += __uint_as_float(v0 << 16) + __uint_as_float(v1 << 16) +
                      __uint_as_float(v2 << 16) + __uint_as_float(v3 << 16);
                a1 += __uint_as_float(v0 & 0xffff0000u) + __uint_as_float(v1 & 0xffff0000u) +
                      __uint_as_float(v2 & 0xffff0000u) + __uint_as_float(v3 & 0xffff0000u);
            } else {
                const float2* p = (const float2*)src_;
                float2 v0 = p[(size_t)c0 * 64 + lane];
                float2 v1 = p[(size_t)c1 * 64 + lane];
                float2 v2 = p[(size_t)c2 * 64 + lane];
                float2 v3 = p[(size_t)c3 * 64 + lane];
                a0 += v0.x + v1.x + v2.x + v3.x;
                a1 += v0.y + v1.y + v2.y + v3.y;
            }
        }
        for (; i < m; ++i) {
            int c = __shfl(ce, i);
            if (BF16) {
                unsigned v = ((const unsigned int*)src_)[(size_t)c * 64 + lane];
                a0 += __uint_as_float(v << 16);
                a1 += __uint_as_float(v & 0xffff0000u);
            } else {
                float2 v = ((const float2*)src_)[(size_t)c * 64 + lane];
                a0 += v.x;
                a1 += v.y;
            }
        }
    }
    unsigned r = ((unsigned)f2bfu(a1) << 16) | (unsigned)f2bfu(a0);
    aggb[(size_t)n * 64 + lane] = r;
}

// h = relu([xin|agg] @ Wcat^T + deg*c + bu).  512 thr = 8 waves; block = 256 nodes.
// B staged in LDS (fragment order, 64KB); mfma 32x32x16; LDS-transpose epilogue.
template <int XF32, int POOL>
__global__ __launch_bounds__(512) void update_kernel(
    const void* __restrict__ xin_, const unsigned int* __restrict__ aggb,
    const int* __restrict__ hist, const float* __restrict__ cvec,
    const float* __restrict__ bupd, const short* __restrict__ Wcatf,
    unsigned int* __restrict__ houtb, float* __restrict__ pooled,
    const int* __restrict__ batch, int N) {
    __shared__ short lds_s[32768];  // 64KB
    const int tid = threadIdx.x;
    const int wave = tid >> 6, lane = tid & 63;
    const int l31 = lane & 31, hi = lane >> 5;

    {  // stage B: linear 64KB copy, coalesced + conflict-free
        const uint4* g = (const uint4*)Wcatf;
        uint4* l4 = (uint4*)lds_s;
#pragma unroll
        for (int j = 0; j < 8; ++j) l4[j * 512 + tid] = g[j * 512 + tid];
    }
    __syncthreads();

    const int m0 = blockIdx.x * 256 + wave * 32;
    int nr = m0 + l31;
    if (nr >= N) nr = N - 1;
    f32x16 acc[4] = {};
#pragma unroll
    for (int step = 0; step < 16; ++step) {
        short8 a;
        if (step < 8) {
            if (XF32) {
                const float* p = (const float*)xin_ + (size_t)nr * 128 + step * 16 + hi * 8;
                float4 f0 = *(const float4*)p;
                float4 f1 = *(const float4*)(p + 4);
                a[0] = f2bf(f0.x); a[1] = f2bf(f0.y); a[2] = f2bf(f0.z); a[3] = f2bf(f0.w);
                a[4] = f2bf(f1.x); a[5] = f2bf(f1.y); a[6] = f2bf(f1.z); a[7] = f2bf(f1.w);
            } else {
                a = *(const short8*)((const short*)xin_ + (size_t)nr * 128 + step * 16 + hi * 8);
            }
        } else {
            a = *(const short8*)((const short*)aggb + (size_t)nr * 128 + (step - 8) * 16 + hi * 8);
        }
#pragma unroll
        for (int ct = 0; ct < 4; ++ct) {
            const short8 b = *(const short8*)(lds_s + (((step * 2 + hi) * 128) + ct * 32 + l31) * 8);
            acc[ct] = __builtin_amdgcn_mfma_f32_32x32x16_bf16(a, b, acc[ct], 0, 0, 0);
        }
    }
    __syncthreads();  // B dead; LDS becomes transpose buffer

    float dv[16];
#pragma unroll
    for (int r = 0; r < 16; ++r) {
        int row = (r & 3) + 8 * (r >> 2) + 4 * hi;
        int node = m0 + row;
        if (node >= N) node = N - 1;
        dv[r] = (float)hist[node];
    }
    short* tp = lds_s + wave * 4096;  // [32][128] bf16 per wave
#pragma unroll
    for (int ct = 0; ct < 4; ++ct) {
        int o = ct * 32 + l31;
        float co = cvec[o], bo = bupd[o];
#pragma unroll
        for (int r = 0; r < 16; ++r) {
            int row = (r & 3) + 8 * (r >> 2) + 4 * hi;
            float v = fmaxf(acc[ct][r] + dv[r] * co + bo, 0.f);
            tp[row * 128 + o] = f2bf(v);
        }
    }
    __syncthreads();

    if (POOL == 0) {
        const uint4* l4 = (const uint4*)tp;
#pragma unroll
        for (int j = 0; j < 8; ++j) {
            int node = m0 + j * 4 + (lane >> 4);
            if (node < N)
                ((uint4*)houtb)[(size_t)m0 * 16 + j * 64 + lane] = l4[j * 64 + lane];
        }
    } else {
        // block-local segmented pool over sorted batch
        int c = tid & 127, seg = tid >> 7;
        int base = blockIdx.x * 256 + seg * 64;
        float s = 0.f;
        int gprev = -1;
        for (int i = 0; i < 64; ++i) {
            int node = base + i;
            if (node >= N) break;
            int g = batch[node];
            if (g != gprev) {
                if (gprev >= 0) atomicAdd(&pooled[gprev * 128 + c], s);
                s = 0.f;
                gprev = g;
            }
            unsigned u = (unsigned short)lds_s[(seg * 64 + i) * 128 + c];
            s += __uint_as_float(u << 16);
        }
        if (gprev >= 0) atomicAdd(&pooled[gprev * 128 + c], s);
    }
}

__global__ void final_kernel(const float* __restrict__ pooled, const float* __restrict__ cnt,
                             const float* __restrict__ Wcls, const float* __restrict__ bcls,
                             float* __restrict__ out) {
    __shared__ float sh[128];
    int g = blockIdx.x;
    int t = threadIdx.x;
    sh[t] = pooled[g * 128 + t] / cnt[g];
    __syncthreads();
    if (t < 10) {
        float s = bcls[t];
        for (int i = 0; i < 128; ++i) s += sh[i] * Wcls[t * 128 + i];
        out[g * 10 + t] = s;
    }
}

extern "C" void kernel_launch(void* const* d_in, const int* in_sizes, int n_in,
                              void* d_out, int out_size, void* d_ws, size_t ws_size,
                              hipStream_t stream) {
    const float* x = (const float*)d_in[0];
    const int* ei = (const int*)d_in[1];
    const int* batch = (const int*)d_in[2];
    const float* Wm1 = (const float*)d_in[3];
    const float* bm1 = (const float*)d_in[4];
    const float* Wu1 = (const float*)d_in[5];
    const float* bu1 = (const float*)d_in[6];
    const float* Wm2 = (const float*)d_in[7];
    const float* bm2 = (const float*)d_in[8];
    const float* Wu2 = (const float*)d_in[9];
    const float* bu2 = (const float*)d_in[10];
    const float* Wcls = (const float*)d_in[11];
    const float* bcls = (const float*)d_in[12];
    float* out = (float*)d_out;

    const int N = N_NODES, E = N_EDGES;
    const int* row = ei;
    const int* col = ei + E;
    const int NB = (N + 255) / 256;       // 196 scan blocks
    const int UB = (N + 255) / 256;       // 196 update blocks (256 nodes each)

    // workspace layout (floats from base); all 16B-aligned where needed
    int* hist = (int*)d_ws;                              // 50000
    int* cursor = hist + 50000;                          // 50000
    float* pooled = (float*)(cursor + 50000);            // 8192
    float* cnt = pooled + 8192;                          // 64
    int* off = (int*)(cnt + 64);                         // 50000
    int* bsum = off + 50000;                             // 256
    int* csr = bsum + 256;                               // 800000
    unsigned int* aggb = (unsigned int*)(csr + 800000);  // 3,200,000
    unsigned int* h1b = aggb + 3200000;                  // 3,200,000
    float* c1 = (float*)(h1b + 3200000);                 // 128
    float* c2 = c1 + 128;                                // 128
    short* Wcatf1 = (short*)(c2 + 128);                  // 32768 shorts
    short* Wcatf2 = Wcatf1 + 32768;                      // 32768 shorts

    hipMemsetAsync(d_ws, 0, (size_t)(50000 + 50000 + 8192 + 64) * 4, stream);

    fold_kernel<<<128, 256, 0, stream>>>(Wu1, Wm1, bm1, Wcatf1, c1);
    fold_kernel<<<128, 256, 0, stream>>>(Wu2, Wm2, bm2, Wcatf2, c2);
    cnt_kernel<<<(N + 255) / 256, 256, 0, stream>>>(batch, cnt, N);

    hist_kernel<<<(E + 255) / 256, 256, 0, stream>>>(row, hist, E);
    scanA_kernel<<<NB, 256, 0, stream>>>(hist, off, bsum, N);
    scanB_kernel<<<1, 256, 0, stream>>>(bsum, NB);
    scanC_kernel<<<NB, 256, 0, stream>>>(off, bsum, N);
    place_kernel<<<(E + 255) / 256, 256, 0, stream>>>(row, col, off, cursor, csr, E);

    // layer 1
    gather_kernel<0><<<(N + 3) / 4, 256, 0, stream>>>(x, off, hist, csr, aggb, N);
    update_kernel<1, 0><<<UB, 512, 0, stream>>>(x, aggb, hist, c1, bu1, Wcatf1,
                                                h1b, nullptr, nullptr, N);
    // layer 2
    gather_kernel<1><<<(N + 3) / 4, 256, 0, stream>>>(h1b, off, hist, csr, aggb, N);
    update_kernel<0, 1><<<UB, 512, 0, stream>>>(h1b, aggb, hist, c2, bu2, Wcatf2,
                                                nullptr, pooled, batch, N);

    final_kernel<<<NUM_GRAPHS, 128, 0, stream>>>(pooled, cnt, Wcls, bcls, out);
}

// Round 4
// 215.821 us; speedup vs baseline: 7.7223x; 1.0809x over previous
//
#include <hip/hip_runtime.h>
#include <hip/hip_bf16.h>

#define N_NODES 50000
#define N_EDGES 800000
#define NUM_GRAPHS 64

typedef __attribute__((ext_vector_type(8))) short short8;
typedef __attribute__((ext_vector_type(16))) float f32x16;

static __device__ __forceinline__ short f2bf(float f) {
    union { __hip_bfloat16 h; short s; } u;
    u.h = __float2bfloat16(f);
    return u.s;
}
static __device__ __forceinline__ unsigned short f2bfu(float f) {
    union { __hip_bfloat16 h; unsigned short s; } u;
    u.h = __float2bfloat16(f);
    return u.s;
}
static __device__ __forceinline__ float bflo(unsigned u) { return __uint_as_float(u << 16); }
static __device__ __forceinline__ float bfhi(unsigned u) { return __uint_as_float(u & 0xffff0000u); }

// x fp32 -> bf16 pairs (packed uint). 8 floats per thread.
__global__ void cvt_kernel(const float* __restrict__ x, uint4* __restrict__ xb, int n8) {
    int i = blockIdx.x * 256 + threadIdx.x;
    if (i >= n8) return;
    const float4* p = (const float4*)(x + (size_t)i * 8);
    float4 f0 = p[0], f1 = p[1];
    uint4 r;
    r.x = ((unsigned)f2bfu(f0.y) << 16) | f2bfu(f0.x);
    r.y = ((unsigned)f2bfu(f0.w) << 16) | f2bfu(f0.z);
    r.z = ((unsigned)f2bfu(f1.y) << 16) | f2bfu(f1.x);
    r.w = ((unsigned)f2bfu(f1.w) << 16) | f2bfu(f1.z);
    xb[i] = r;
}

// Both layers' weight folds in one launch. Wcatf fragment order as in R3.
__global__ void fold_kernel(const float* __restrict__ Wu1, const float* __restrict__ Wm1,
                            const float* __restrict__ bm1, short* __restrict__ Wcatf1,
                            float* __restrict__ c1,
                            const float* __restrict__ Wu2, const float* __restrict__ Wm2,
                            const float* __restrict__ bm2, short* __restrict__ Wcatf2,
                            float* __restrict__ c2) {
    int layer = blockIdx.x >> 7;
    int o = blockIdx.x & 127;
    int k = threadIdx.x;  // 0..255
    const float* Wu = layer ? Wu2 : Wu1;
    const float* Wm = layer ? Wm2 : Wm1;
    const float* bm = layer ? bm2 : bm1;
    short* Wcatf = layer ? Wcatf2 : Wcatf1;
    float* cvec = layer ? c2 : c1;
    float val;
    if (k < 128) {
        val = Wu[o * 256 + k];
    } else {
        int kk = k - 128;
        float s = 0.f;
        for (int j = 0; j < 128; ++j) s += Wu[o * 256 + 128 + j] * Wm[j * 128 + kk];
        val = s;
    }
    Wcatf[(((k >> 3) * 128) + o) * 8 + (k & 7)] = f2bf(val);
    if (k == 0) {
        float cs = 0.f;
        for (int j = 0; j < 128; ++j) cs += Wu[o * 256 + 128 + j] * bm[j];
        cvec[o] = cs;
    }
}

// hist over E rows + per-graph node counts (batch sorted) in one kernel.
__global__ void hist_cnt_kernel(const int* __restrict__ row, int* __restrict__ hist, int E,
                                const int* __restrict__ batch, float* __restrict__ cnt, int N) {
    __shared__ float loc[NUM_GRAPHS];
    int t = threadIdx.x;
    int e = blockIdx.x * 256 + t;
    bool doCnt = (blockIdx.x * 256 < N);
    if (doCnt) {
        if (t < NUM_GRAPHS) loc[t] = 0.f;
        __syncthreads();
    }
    if (e < E) atomicAdd(&hist[row[e]], 1);
    if (doCnt) {
        if (e < N) atomicAdd(&loc[batch[e]], 1.0f);
        __syncthreads();
        if (t < NUM_GRAPHS && loc[t] != 0.f) atomicAdd(&cnt[t], loc[t]);
    }
}

__global__ void scanA_kernel(const int* __restrict__ hist, int* __restrict__ off,
                             int* __restrict__ bsum, int N) {
    __shared__ int sh[256];
    int t = threadIdx.x, idx = blockIdx.x * 256 + t;
    int v = (idx < N) ? hist[idx] : 0;
    sh[t] = v;
    __syncthreads();
    for (int o = 1; o < 256; o <<= 1) {
        int a = (t >= o) ? sh[t - o] : 0;
        __syncthreads();
        sh[t] += a;
        __syncthreads();
    }
    if (idx < N) off[idx] = sh[t] - v;
    if (t == 255) bsum[blockIdx.x] = sh[255];
}

__global__ void scanB_kernel(int* __restrict__ bsum, int nb) {
    __shared__ int sh[256];
    int t = threadIdx.x;
    int v = (t < nb) ? bsum[t] : 0;
    sh[t] = v;
    __syncthreads();
    for (int o = 1; o < 256; o <<= 1) {
        int a = (t >= o) ? sh[t - o] : 0;
        __syncthreads();
        sh[t] += a;
        __syncthreads();
    }
    if (t < nb) bsum[t] = sh[t] - v;  // exclusive
}

__global__ void scanC_kernel(int* __restrict__ off, const int* __restrict__ bsum, int N) {
    int idx = blockIdx.x * 256 + threadIdx.x;
    if (idx < N) off[idx] += bsum[blockIdx.x];
}

__global__ void place_kernel(const int* __restrict__ row, const int* __restrict__ col,
                             const int* __restrict__ off, int* __restrict__ cursor,
                             int* __restrict__ csr, int E) {
    int e = blockIdx.x * 256 + threadIdx.x;
    if (e < E) {
        int r = row[e];
        int pos = off[r] + atomicAdd(&cursor[r], 1);
        csr[pos] = col[e];
    }
}

// agg[n] = sum of src rows (bf16) over csr neighbors. One wave per node.
// 16 lanes x 16B cover one 256B row; 4 neighbors in flight per load instruction.
__global__ __launch_bounds__(256) void gather_kernel(const unsigned short* __restrict__ src,
                                                     const int* __restrict__ off,
                                                     const int* __restrict__ hist,
                                                     const int* __restrict__ csr,
                                                     unsigned int* __restrict__ aggb, int N) {
    int wave = threadIdx.x >> 6, lane = threadIdx.x & 63;
    int n = blockIdx.x * 4 + wave;
    if (n >= N) return;
    int s = off[n];
    int e = s + hist[n];
    int grp = lane >> 4, sub = lane & 15;
    float a0 = 0.f, a1 = 0.f, a2 = 0.f, a3 = 0.f, a4 = 0.f, a5 = 0.f, a6 = 0.f, a7 = 0.f;
    for (int base = s; base < e; base += 64) {
        int m = e - base;
        if (m > 64) m = 64;
        int ce = (base + lane < e) ? csr[base + lane] : 0;
        int iters = (m + 3) >> 2;
#pragma unroll 2
        for (int i = 0; i < iters; ++i) {
            int idx = i * 4 + grp;
            int c = __shfl(ce, idx);
            uint4 v = *(const uint4*)(src + (size_t)c * 128 + sub * 8);
            if (idx >= m) { v.x = 0; v.y = 0; v.z = 0; v.w = 0; }
            a0 += bflo(v.x); a1 += bfhi(v.x);
            a2 += bflo(v.y); a3 += bfhi(v.y);
            a4 += bflo(v.z); a5 += bfhi(v.z);
            a6 += bflo(v.w); a7 += bfhi(v.w);
        }
    }
#pragma unroll
    for (int mk = 16; mk <= 32; mk <<= 1) {
        a0 += __shfl_xor(a0, mk); a1 += __shfl_xor(a1, mk);
        a2 += __shfl_xor(a2, mk); a3 += __shfl_xor(a3, mk);
        a4 += __shfl_xor(a4, mk); a5 += __shfl_xor(a5, mk);
        a6 += __shfl_xor(a6, mk); a7 += __shfl_xor(a7, mk);
    }
    if (grp == 0) {
        uint4 r;
        r.x = ((unsigned)f2bfu(a1) << 16) | f2bfu(a0);
        r.y = ((unsigned)f2bfu(a3) << 16) | f2bfu(a2);
        r.z = ((unsigned)f2bfu(a5) << 16) | f2bfu(a4);
        r.w = ((unsigned)f2bfu(a7) << 16) | f2bfu(a6);
        ((uint4*)aggb)[(size_t)n * 16 + sub] = r;
    }
}

// h = relu([xin|agg] @ Wcat^T + deg*c + bu).  512 thr = 8 waves; block = 256 nodes.
// B staged in LDS (fragment order, 64KB); mfma 32x32x16; LDS-transpose epilogue.
template <int POOL>
__global__ __launch_bounds__(512) void update_kernel(
    const void* __restrict__ xin_, const unsigned int* __restrict__ aggb,
    const int* __restrict__ hist, const float* __restrict__ cvec,
    const float* __restrict__ bupd, const short* __restrict__ Wcatf,
    unsigned int* __restrict__ houtb, float* __restrict__ pooled,
    const int* __restrict__ batch, int N) {
    __shared__ short lds_s[32768];  // 64KB
    const int tid = threadIdx.x;
    const int wave = tid >> 6, lane = tid & 63;
    const int l31 = lane & 31, hi = lane >> 5;

    {  // stage B: linear 64KB copy, coalesced + conflict-free
        const uint4* g = (const uint4*)Wcatf;
        uint4* l4 = (uint4*)lds_s;
#pragma unroll
        for (int j = 0; j < 8; ++j) l4[j * 512 + tid] = g[j * 512 + tid];
    }
    __syncthreads();

    const int m0 = blockIdx.x * 256 + wave * 32;
    int nr = m0 + l31;
    if (nr >= N) nr = N - 1;
    f32x16 acc[4] = {};
#pragma unroll
    for (int step = 0; step < 16; ++step) {
        short8 a;
        if (step < 8) {
            a = *(const short8*)((const short*)xin_ + (size_t)nr * 128 + step * 16 + hi * 8);
        } else {
            a = *(const short8*)((const short*)aggb + (size_t)nr * 128 + (step - 8) * 16 + hi * 8);
        }
#pragma unroll
        for (int ct = 0; ct < 4; ++ct) {
            const short8 b = *(const short8*)(lds_s + (((step * 2 + hi) * 128) + ct * 32 + l31) * 8);
            acc[ct] = __builtin_amdgcn_mfma_f32_32x32x16_bf16(a, b, acc[ct], 0, 0, 0);
        }
    }
    __syncthreads();  // B dead; LDS becomes transpose buffer

    float dv[16];
#pragma unroll
    for (int r = 0; r < 16; ++r) {
        int row = (r & 3) + 8 * (r >> 2) + 4 * hi;
        int node = m0 + row;
        if (node >= N) node = N - 1;
        dv[r] = (float)hist[node];
    }
    short* tp = lds_s + wave * 4096;  // [32][128] bf16 per wave
#pragma unroll
    for (int ct = 0; ct < 4; ++ct) {
        int o = ct * 32 + l31;
        float co = cvec[o], bo = bupd[o];
#pragma unroll
        for (int r = 0; r < 16; ++r) {
            int row = (r & 3) + 8 * (r >> 2) + 4 * hi;
            float v = fmaxf(acc[ct][r] + dv[r] * co + bo, 0.f);
            tp[row * 128 + o] = f2bf(v);
        }
    }
    __syncthreads();

    if (POOL == 0) {
        const uint4* l4 = (const uint4*)tp;
#pragma unroll
        for (int j = 0; j < 8; ++j) {
            int node = m0 + j * 4 + (lane >> 4);
            if (node < N)
                ((uint4*)houtb)[(size_t)m0 * 16 + j * 64 + lane] = l4[j * 64 + lane];
        }
    } else {
        // block-local segmented pool over sorted batch
        int c = tid & 127, seg = tid >> 7;
        int base = blockIdx.x * 256 + seg * 64;
        float s = 0.f;
        int gprev = -1;
        for (int i = 0; i < 64; ++i) {
            int node = base + i;
            if (node >= N) break;
            int g = batch[node];
            if (g != gprev) {
                if (gprev >= 0) atomicAdd(&pooled[gprev * 128 + c], s);
                s = 0.f;
                gprev = g;
            }
            unsigned u = (unsigned short)lds_s[(seg * 64 + i) * 128 + c];
            s += __uint_as_float(u << 16);
        }
        if (gprev >= 0) atomicAdd(&pooled[gprev * 128 + c], s);
    }
}

__global__ void final_kernel(const float* __restrict__ pooled, const float* __restrict__ cnt,
                             const float* __restrict__ Wcls, const float* __restrict__ bcls,
                             float* __restrict__ out) {
    __shared__ float sh[128];
    int g = blockIdx.x;
    int t = threadIdx.x;
    sh[t] = pooled[g * 128 + t] / cnt[g];
    __syncthreads();
    if (t < 10) {
        float s = bcls[t];
        for (int i = 0; i < 128; ++i) s += sh[i] * Wcls[t * 128 + i];
        out[g * 10 + t] = s;
    }
}

extern "C" void kernel_launch(void* const* d_in, const int* in_sizes, int n_in,
                              void* d_out, int out_size, void* d_ws, size_t ws_size,
                              hipStream_t stream) {
    const float* x = (const float*)d_in[0];
    const int* ei = (const int*)d_in[1];
    const int* batch = (const int*)d_in[2];
    const float* Wm1 = (const float*)d_in[3];
    const float* bm1 = (const float*)d_in[4];
    const float* Wu1 = (const float*)d_in[5];
    const float* bu1 = (const float*)d_in[6];
    const float* Wm2 = (const float*)d_in[7];
    const float* bm2 = (const float*)d_in[8];
    const float* Wu2 = (const float*)d_in[9];
    const float* bu2 = (const float*)d_in[10];
    const float* Wcls = (const float*)d_in[11];
    const float* bcls = (const float*)d_in[12];
    float* out = (float*)d_out;

    const int N = N_NODES, E = N_EDGES;
    const int* row = ei;
    const int* col = ei + E;
    const int NB = (N + 255) / 256;  // 196
    const int UB = (N + 255) / 256;  // 196

    // workspace layout
    int* hist = (int*)d_ws;                              // 50000
    int* cursor = hist + 50000;                          // 50000
    float* pooled = (float*)(cursor + 50000);            // 8192
    float* cnt = pooled + 8192;                          // 64
    int* off = (int*)(cnt + 64);                         // 50000
    int* bsum = off + 50000;                             // 256
    int* csr = bsum + 256;                               // 800000
    unsigned int* aggb = (unsigned int*)(csr + 800000);  // 3,200,000
    unsigned int* h1b = aggb + 3200000;                  // 3,200,000
    unsigned int* xb = h1b + 3200000;                    // 3,200,000 (x in bf16)
    float* c1 = (float*)(xb + 3200000);                  // 128
    float* c2 = c1 + 128;                                // 128
    short* Wcatf1 = (short*)(c2 + 128);                  // 32768 shorts
    short* Wcatf2 = Wcatf1 + 32768;                      // 32768 shorts

    hipMemsetAsync(d_ws, 0, (size_t)(50000 + 50000 + 8192 + 64) * 4, stream);

    cvt_kernel<<<(800000 + 255) / 256, 256, 0, stream>>>(x, (uint4*)xb, 800000);
    fold_kernel<<<256, 256, 0, stream>>>(Wu1, Wm1, bm1, Wcatf1, c1,
                                         Wu2, Wm2, bm2, Wcatf2, c2);
    hist_cnt_kernel<<<(E + 255) / 256, 256, 0, stream>>>(row, hist, E, batch, cnt, N);
    scanA_kernel<<<NB, 256, 0, stream>>>(hist, off, bsum, N);
    scanB_kernel<<<1, 256, 0, stream>>>(bsum, NB);
    scanC_kernel<<<NB, 256, 0, stream>>>(off, bsum, N);
    place_kernel<<<(E + 255) / 256, 256, 0, stream>>>(row, col, off, cursor, csr, E);

    // layer 1
    gather_kernel<<<(N + 3) / 4, 256, 0, stream>>>((const unsigned short*)xb, off, hist,
                                                   csr, aggb, N);
    update_kernel<0><<<UB, 512, 0, stream>>>(xb, aggb, hist, c1, bu1, Wcatf1,
                                             h1b, nullptr, nullptr, N);
    // layer 2
    gather_kernel<<<(N + 3) / 4, 256, 0, stream>>>((const unsigned short*)h1b, off, hist,
                                                   csr, aggb, N);
    update_kernel<1><<<UB, 512, 0, stream>>>(h1b, aggb, hist, c2, bu2, Wcatf2,
                                             nullptr, pooled, batch, N);

    final_kernel<<<NUM_GRAPHS, 128, 0, stream>>>(pooled, cnt, Wcls, bcls, out);
}

// Round 5
// 152.356 us; speedup vs baseline: 10.9391x; 1.4166x over previous
//
#include <hip/hip_runtime.h>
#include <hip/hip_bf16.h>

#define N_NODES 50000
#define N_EDGES 800000
#define NUM_GRAPHS 64
#define NBUCK 391  // ceil(50000/128)

typedef __attribute__((ext_vector_type(8))) short short8;
typedef __attribute__((ext_vector_type(16))) float f32x16;

static __device__ __forceinline__ short f2bf(float f) {
    union { __hip_bfloat16 h; short s; } u;
    u.h = __float2bfloat16(f);
    return u.s;
}
static __device__ __forceinline__ unsigned short f2bfu(float f) {
    union { __hip_bfloat16 h; unsigned short s; } u;
    u.h = __float2bfloat16(f);
    return u.s;
}
static __device__ __forceinline__ float bflo(unsigned u) { return __uint_as_float(u << 16); }
static __device__ __forceinline__ float bfhi(unsigned u) { return __uint_as_float(u & 0xffff0000u); }

// x fp32 -> bf16 pairs (packed uint). 8 floats per thread.
__global__ void cvt_kernel(const float* __restrict__ x, uint4* __restrict__ xb, int n8) {
    int i = blockIdx.x * 256 + threadIdx.x;
    if (i >= n8) return;
    const float4* p = (const float4*)(x + (size_t)i * 8);
    float4 f0 = p[0], f1 = p[1];
    uint4 r;
    r.x = ((unsigned)f2bfu(f0.y) << 16) | f2bfu(f0.x);
    r.y = ((unsigned)f2bfu(f0.w) << 16) | f2bfu(f0.z);
    r.z = ((unsigned)f2bfu(f1.y) << 16) | f2bfu(f1.x);
    r.w = ((unsigned)f2bfu(f1.w) << 16) | f2bfu(f1.z);
    xb[i] = r;
}

// Both layers' weight folds in one launch. Wcatf fragment order (frag=(k>>3)*128+o).
__global__ void fold_kernel(const float* __restrict__ Wu1, const float* __restrict__ Wm1,
                            const float* __restrict__ bm1, short* __restrict__ Wcatf1,
                            float* __restrict__ c1,
                            const float* __restrict__ Wu2, const float* __restrict__ Wm2,
                            const float* __restrict__ bm2, short* __restrict__ Wcatf2,
                            float* __restrict__ c2) {
    int layer = blockIdx.x >> 7;
    int o = blockIdx.x & 127;
    int k = threadIdx.x;  // 0..255
    const float* Wu = layer ? Wu2 : Wu1;
    const float* Wm = layer ? Wm2 : Wm1;
    const float* bm = layer ? bm2 : bm1;
    short* Wcatf = layer ? Wcatf2 : Wcatf1;
    float* cvec = layer ? c2 : c1;
    float val;
    if (k < 128) {
        val = Wu[o * 256 + k];
    } else {
        int kk = k - 128;
        float s = 0.f;
        for (int j = 0; j < 128; ++j) s += Wu[o * 256 + 128 + j] * Wm[j * 128 + kk];
        val = s;
    }
    Wcatf[(((k >> 3) * 128) + o) * 8 + (k & 7)] = f2bf(val);
    if (k == 0) {
        float cs = 0.f;
        for (int j = 0; j < 128; ++j) cs += Wu[o * 256 + 128 + j] * bm[j];
        cvec[o] = cs;
    }
}

// per-graph node counts (batch sorted, 64 graphs)
__global__ void cnt_kernel(const int* __restrict__ batch, float* __restrict__ cnt, int N) {
    __shared__ float loc[NUM_GRAPHS];
    int t = threadIdx.x;
    if (t < NUM_GRAPHS) loc[t] = 0.f;
    __syncthreads();
    int n = blockIdx.x * 256 + t;
    if (n < N) atomicAdd(&loc[batch[n]], 1.0f);
    __syncthreads();
    if (t < NUM_GRAPHS && loc[t] != 0.f) atomicAdd(&cnt[t], loc[t]);
}

// ---- bucket-sorted CSR build: bucket = row>>7 (128 rows per bucket) ----
__global__ __launch_bounds__(1024) void binhist_kernel(const int* __restrict__ row,
                                                       int* __restrict__ bhist, int E) {
    __shared__ int lh[NBUCK];
    int t = threadIdx.x;
    for (int i = t; i < NBUCK; i += 1024) lh[i] = 0;
    __syncthreads();
    int e0 = blockIdx.x * 4096;
#pragma unroll
    for (int k = 0; k < 4; ++k) {
        int e = e0 + k * 1024 + t;
        if (e < E) atomicAdd(&lh[row[e] >> 7], 1);
    }
    __syncthreads();
    for (int i = t; i < NBUCK; i += 1024)
        if (lh[i]) atomicAdd(&bhist[i], lh[i]);
}

// exclusive scan of bhist -> bbase[0..NBUCK] (bbase[NBUCK]=E), bcur=base
__global__ void bscan_kernel(const int* __restrict__ bhist, int* __restrict__ bbase,
                             int* __restrict__ bcur) {
    __shared__ int s[512];
    int t = threadIdx.x;
    int v = (t < NBUCK) ? bhist[t] : 0;
    s[t] = v;
    __syncthreads();
    for (int o = 1; o < 512; o <<= 1) {
        int a = (t >= o) ? s[t - o] : 0;
        __syncthreads();
        s[t] += a;
        __syncthreads();
    }
    if (t <= NBUCK) bbase[t] = s[t] - ((t < NBUCK) ? bhist[t] : 0);
    if (t < NBUCK) bcur[t] = s[t] - bhist[t];
}

// pass A: bin edges by bucket through LDS; write packed (row<<16|col) runs contiguously
__global__ __launch_bounds__(1024) void binA_kernel(const int* __restrict__ row,
                                                    const int* __restrict__ col,
                                                    int* __restrict__ bcur,
                                                    unsigned* __restrict__ ebin, int E) {
    __shared__ int lcur[NBUCK];
    __shared__ int lscan[NBUCK];
    __shared__ int gbase[NBUCK];
    __shared__ int sscan[512];
    __shared__ unsigned stage[4096];
    int t = threadIdx.x;
    for (int i = t; i < NBUCK; i += 1024) lcur[i] = 0;
    __syncthreads();
    int e0 = blockIdx.x * 4096;
    unsigned pv[4];
    int pb[4], pr[4];
#pragma unroll
    for (int k = 0; k < 4; ++k) {
        int e = e0 + k * 1024 + t;
        if (e < E) {
            int r = row[e], c = col[e];
            pv[k] = ((unsigned)r << 16) | (unsigned)c;
            pb[k] = r >> 7;
            pr[k] = atomicAdd(&lcur[pb[k]], 1);
        } else {
            pb[k] = -1;
        }
    }
    __syncthreads();
    if (t < 512) sscan[t] = (t < NBUCK) ? lcur[t] : 0;
    __syncthreads();
    for (int o = 1; o < 512; o <<= 1) {
        int a = 0;
        if (t < 512 && t >= o) a = sscan[t - o];
        __syncthreads();
        if (t < 512) sscan[t] += a;
        __syncthreads();
    }
    if (t < NBUCK) lscan[t] = sscan[t] - lcur[t];
    __syncthreads();
    for (int i = t; i < NBUCK; i += 1024) {
        int c = lcur[i];
        gbase[i] = c ? atomicAdd(&bcur[i], c) : 0;
    }
#pragma unroll
    for (int k = 0; k < 4; ++k)
        if (pb[k] >= 0) stage[lscan[pb[k]] + pr[k]] = pv[k];
    __syncthreads();
    int total = E - e0;
    if (total > 4096) total = 4096;
    for (int idx = t; idx < total; idx += 1024) {
        unsigned v = stage[idx];
        int b = v >> 23;
        ebin[gbase[b] + (idx - lscan[b])] = v;
    }
}

// pass B: per bucket, build csr segment + hist + off entirely in LDS, write coalesced
__global__ __launch_bounds__(256) void binB_kernel(const unsigned* __restrict__ ebin,
                                                   const int* __restrict__ bbase,
                                                   const int* __restrict__ bcur,
                                                   int* __restrict__ csr,
                                                   int* __restrict__ hist,
                                                   int* __restrict__ off, int N) {
    __shared__ int lcnt[128];
    __shared__ int loff[128];
    __shared__ int lcur2[128];
    __shared__ int sscan[128];
    __shared__ unsigned short stage[4096];
    int b = blockIdx.x, t = threadIdx.x;
    int base = bbase[b];
    int n = bcur[b] - base;
    if (n > 4096) n = 4096;  // safety clamp (cannot occur for this input)
    if (t < 128) lcnt[t] = 0;
    __syncthreads();
    for (int idx = t; idx < n; idx += 256) {
        unsigned v = ebin[base + idx];
        atomicAdd(&lcnt[(v >> 16) & 127], 1);
    }
    __syncthreads();
    if (t < 128) sscan[t] = lcnt[t];
    __syncthreads();
    for (int o = 1; o < 128; o <<= 1) {
        int a = 0;
        if (t < 128 && t >= o) a = sscan[t - o];
        __syncthreads();
        if (t < 128) sscan[t] += a;
        __syncthreads();
    }
    if (t < 128) {
        loff[t] = sscan[t] - lcnt[t];
        lcur2[t] = sscan[t] - lcnt[t];
    }
    __syncthreads();
    for (int idx = t; idx < n; idx += 256) {
        unsigned v = ebin[base + idx];
        int lr = (v >> 16) & 127;
        int pos = atomicAdd(&lcur2[lr], 1);
        stage[pos] = (unsigned short)(v & 0xffffu);
    }
    __syncthreads();
    for (int idx = t; idx < n; idx += 256) csr[base + idx] = (int)stage[idx];
    int r0 = b * 128;
    if (t < 128 && r0 + t < N) {
        hist[r0 + t] = lcnt[t];
        off[r0 + t] = base + loff[t];
    }
}

// agg[n] = sum of src rows (bf16) over csr neighbors. One wave per node.
// 16 lanes x 16B cover one 256B row; 4 neighbors per load instr, unroll 4.
__global__ __launch_bounds__(256) void gather_kernel(const unsigned short* __restrict__ src,
                                                     const int* __restrict__ off,
                                                     const int* __restrict__ hist,
                                                     const int* __restrict__ csr,
                                                     unsigned int* __restrict__ aggb, int N) {
    int wave = threadIdx.x >> 6, lane = threadIdx.x & 63;
    int n = blockIdx.x * 4 + wave;
    if (n >= N) return;
    int s = off[n];
    int e = s + hist[n];
    int grp = lane >> 4, sub = lane & 15;
    float a0 = 0.f, a1 = 0.f, a2 = 0.f, a3 = 0.f, a4 = 0.f, a5 = 0.f, a6 = 0.f, a7 = 0.f;
    for (int base = s; base < e; base += 64) {
        int m = e - base;
        if (m > 64) m = 64;
        int ce = (base + lane < e) ? csr[base + lane] : 0;
        int iters = (m + 3) >> 2;
#pragma unroll 4
        for (int i = 0; i < iters; ++i) {
            int idx = i * 4 + grp;
            int c = __shfl(ce, idx);
            uint4 v = *(const uint4*)(src + (size_t)c * 128 + sub * 8);
            if (idx >= m) { v.x = 0; v.y = 0; v.z = 0; v.w = 0; }
            a0 += bflo(v.x); a1 += bfhi(v.x);
            a2 += bflo(v.y); a3 += bfhi(v.y);
            a4 += bflo(v.z); a5 += bfhi(v.z);
            a6 += bflo(v.w); a7 += bfhi(v.w);
        }
    }
#pragma unroll
    for (int mk = 16; mk <= 32; mk <<= 1) {
        a0 += __shfl_xor(a0, mk); a1 += __shfl_xor(a1, mk);
        a2 += __shfl_xor(a2, mk); a3 += __shfl_xor(a3, mk);
        a4 += __shfl_xor(a4, mk); a5 += __shfl_xor(a5, mk);
        a6 += __shfl_xor(a6, mk); a7 += __shfl_xor(a7, mk);
    }
    if (grp == 0) {
        uint4 r;
        r.x = ((unsigned)f2bfu(a1) << 16) | f2bfu(a0);
        r.y = ((unsigned)f2bfu(a3) << 16) | f2bfu(a2);
        r.z = ((unsigned)f2bfu(a5) << 16) | f2bfu(a4);
        r.w = ((unsigned)f2bfu(a7) << 16) | f2bfu(a6);
        ((uint4*)aggb)[(size_t)n * 16 + sub] = r;
    }
}

// h = relu([xin|agg] @ Wcat^T + deg*c + bu).  512 thr = 8 waves; block = 256 nodes.
template <int POOL>
__global__ __launch_bounds__(512) void update_kernel(
    const void* __restrict__ xin_, const unsigned int* __restrict__ aggb,
    const int* __restrict__ hist, const float* __restrict__ cvec,
    const float* __restrict__ bupd, const short* __restrict__ Wcatf,
    unsigned int* __restrict__ houtb, float* __restrict__ pooled,
    const int* __restrict__ batch, int N) {
    __shared__ short lds_s[32768];  // 64KB
    const int tid = threadIdx.x;
    const int wave = tid >> 6, lane = tid & 63;
    const int l31 = lane & 31, hi = lane >> 5;

    {  // stage B: linear 64KB copy
        const uint4* g = (const uint4*)Wcatf;
        uint4* l4 = (uint4*)lds_s;
#pragma unroll
        for (int j = 0; j < 8; ++j) l4[j * 512 + tid] = g[j * 512 + tid];
    }
    __syncthreads();

    const int m0 = blockIdx.x * 256 + wave * 32;
    int nr = m0 + l31;
    if (nr >= N) nr = N - 1;
    f32x16 acc[4] = {};
#pragma unroll
    for (int step = 0; step < 16; ++step) {
        short8 a;
        if (step < 8) {
            a = *(const short8*)((const short*)xin_ + (size_t)nr * 128 + step * 16 + hi * 8);
        } else {
            a = *(const short8*)((const short*)aggb + (size_t)nr * 128 + (step - 8) * 16 + hi * 8);
        }
#pragma unroll
        for (int ct = 0; ct < 4; ++ct) {
            const short8 b = *(const short8*)(lds_s + (((step * 2 + hi) * 128) + ct * 32 + l31) * 8);
            acc[ct] = __builtin_amdgcn_mfma_f32_32x32x16_bf16(a, b, acc[ct], 0, 0, 0);
        }
    }
    __syncthreads();  // B dead; LDS becomes transpose buffer

    float dv[16];
#pragma unroll
    for (int r = 0; r < 16; ++r) {
        int row = (r & 3) + 8 * (r >> 2) + 4 * hi;
        int node = m0 + row;
        if (node >= N) node = N - 1;
        dv[r] = (float)hist[node];
    }
    short* tp = lds_s + wave * 4096;  // [32][128] bf16 per wave
#pragma unroll
    for (int ct = 0; ct < 4; ++ct) {
        int o = ct * 32 + l31;
        float co = cvec[o], bo = bupd[o];
#pragma unroll
        for (int r = 0; r < 16; ++r) {
            int row = (r & 3) + 8 * (r >> 2) + 4 * hi;
            float v = fmaxf(acc[ct][r] + dv[r] * co + bo, 0.f);
            tp[row * 128 + o] = f2bf(v);
        }
    }
    __syncthreads();

    if (POOL == 0) {
        const uint4* l4 = (const uint4*)tp;
#pragma unroll
        for (int j = 0; j < 8; ++j) {
            int node = m0 + j * 4 + (lane >> 4);
            if (node < N)
                ((uint4*)houtb)[(size_t)m0 * 16 + j * 64 + lane] = l4[j * 64 + lane];
        }
    } else {
        // block-local segmented pool over sorted batch
        int c = tid & 127, seg = tid >> 7;
        int base = blockIdx.x * 256 + seg * 64;
        float s = 0.f;
        int gprev = -1;
        for (int i = 0; i < 64; ++i) {
            int node = base + i;
            if (node >= N) break;
            int g = batch[node];
            if (g != gprev) {
                if (gprev >= 0) atomicAdd(&pooled[gprev * 128 + c], s);
                s = 0.f;
                gprev = g;
            }
            unsigned u = (unsigned short)lds_s[(seg * 64 + i) * 128 + c];
            s += __uint_as_float(u << 16);
        }
        if (gprev >= 0) atomicAdd(&pooled[gprev * 128 + c], s);
    }
}

__global__ void final_kernel(const float* __restrict__ pooled, const float* __restrict__ cnt,
                             const float* __restrict__ Wcls, const float* __restrict__ bcls,
                             float* __restrict__ out) {
    __shared__ float sh[128];
    int g = blockIdx.x;
    int t = threadIdx.x;
    sh[t] = pooled[g * 128 + t] / cnt[g];
    __syncthreads();
    if (t < 10) {
        float s = bcls[t];
        for (int i = 0; i < 128; ++i) s += sh[i] * Wcls[t * 128 + i];
        out[g * 10 + t] = s;
    }
}

extern "C" void kernel_launch(void* const* d_in, const int* in_sizes, int n_in,
                              void* d_out, int out_size, void* d_ws, size_t ws_size,
                              hipStream_t stream) {
    const float* x = (const float*)d_in[0];
    const int* ei = (const int*)d_in[1];
    const int* batch = (const int*)d_in[2];
    const float* Wm1 = (const float*)d_in[3];
    const float* bm1 = (const float*)d_in[4];
    const float* Wu1 = (const float*)d_in[5];
    const float* bu1 = (const float*)d_in[6];
    const float* Wm2 = (const float*)d_in[7];
    const float* bm2 = (const float*)d_in[8];
    const float* Wu2 = (const float*)d_in[9];
    const float* bu2 = (const float*)d_in[10];
    const float* Wcls = (const float*)d_in[11];
    const float* bcls = (const float*)d_in[12];
    float* out = (float*)d_out;

    const int N = N_NODES, E = N_EDGES;
    const int* row = ei;
    const int* col = ei + E;
    const int EB = (E + 4095) / 4096;  // 196 binning blocks
    const int UB = (N + 255) / 256;    // 196 update blocks

    // workspace layout (int units from base)
    int* bhist = (int*)d_ws;                     // 512
    float* cnt = (float*)(bhist + 512);          // 64
    float* pooled = cnt + 64;                    // 8192
    int* bbase = (int*)(pooled + 8192);          // 512 (needs NBUCK+1)
    int* bcur = bbase + 512;                     // 512
    int* hist = bcur + 512;                      // 50000
    int* off = hist + 50000;                     // 50000
    unsigned* ebin = (unsigned*)(off + 50000);   // 800000
    int* csr = (int*)(ebin + 800000);            // 800000
    unsigned* aggb = (unsigned*)(csr + 800000);  // 3,200,000
    unsigned* h1b = aggb + 3200000;              // 3,200,000
    unsigned* xb = h1b + 3200000;                // 3,200,000
    float* c1 = (float*)(xb + 3200000);          // 128
    float* c2 = c1 + 128;                        // 128
    short* Wcatf1 = (short*)(c2 + 128);          // 32768 shorts
    short* Wcatf2 = Wcatf1 + 32768;              // 32768 shorts

    // zero bhist + cnt + pooled (contiguous)
    hipMemsetAsync(d_ws, 0, (size_t)(512 + 64 + 8192) * 4, stream);

    cvt_kernel<<<(800000 + 255) / 256, 256, 0, stream>>>(x, (uint4*)xb, 800000);
    fold_kernel<<<256, 256, 0, stream>>>(Wu1, Wm1, bm1, Wcatf1, c1,
                                         Wu2, Wm2, bm2, Wcatf2, c2);
    cnt_kernel<<<(N + 255) / 256, 256, 0, stream>>>(batch, cnt, N);

    binhist_kernel<<<EB, 1024, 0, stream>>>(row, bhist, E);
    bscan_kernel<<<1, 512, 0, stream>>>(bhist, bbase, bcur);
    binA_kernel<<<EB, 1024, 0, stream>>>(row, col, bcur, ebin, E);
    binB_kernel<<<NBUCK, 256, 0, stream>>>(ebin, bbase, bcur, csr, hist, off, N);

    // layer 1
    gather_kernel<<<(N + 3) / 4, 256, 0, stream>>>((const unsigned short*)xb, off, hist,
                                                   csr, aggb, N);
    update_kernel<0><<<UB, 512, 0, stream>>>(xb, aggb, hist, c1, bu1, Wcatf1,
                                             h1b, nullptr, nullptr, N);
    // layer 2
    gather_kernel<<<(N + 3) / 4, 256, 0, stream>>>((const unsigned short*)h1b, off, hist,
                                                   csr, aggb, N);
    update_kernel<1><<<UB, 512, 0, stream>>>(h1b, aggb, hist, c2, bu2, Wcatf2,
                                             nullptr, pooled, batch, N);

    final_kernel<<<NUM_GRAPHS, 128, 0, stream>>>(pooled, cnt, Wcls, bcls, out);
}

// Round 6
// 143.856 us; speedup vs baseline: 11.5855x; 1.0591x over previous
//
#include <hip/hip_runtime.h>
#include <hip/hip_bf16.h>

#define N_NODES 50000
#define N_EDGES 800000
#define NUM_GRAPHS 64
#define NBUCK 391  // ceil(50000/128)

typedef __attribute__((ext_vector_type(8))) short short8;
typedef __attribute__((ext_vector_type(16))) float f32x16;

static __device__ __forceinline__ short f2bf(float f) {
    union { __hip_bfloat16 h; short s; } u;
    u.h = __float2bfloat16(f);
    return u.s;
}
static __device__ __forceinline__ unsigned short f2bfu(float f) {
    union { __hip_bfloat16 h; unsigned short s; } u;
    u.h = __float2bfloat16(f);
    return u.s;
}
static __device__ __forceinline__ float bflo(unsigned u) { return __uint_as_float(u << 16); }
static __device__ __forceinline__ float bfhi(unsigned u) { return __uint_as_float(u & 0xffff0000u); }

// Fused: x->bf16 convert (blocks 0..3124) | weight folds (blocks 3125..3380)
//        | zero bhist+pooled (blocks 3381..3414)
__global__ __launch_bounds__(256) void prep_kernel(
    const float* __restrict__ x, uint4* __restrict__ xb,
    const float* __restrict__ Wu1, const float* __restrict__ Wm1,
    const float* __restrict__ bm1, short* __restrict__ Wcatf1, float* __restrict__ c1,
    const float* __restrict__ Wu2, const float* __restrict__ Wm2,
    const float* __restrict__ bm2, short* __restrict__ Wcatf2, float* __restrict__ c2,
    int* __restrict__ zbase) {
    int bid = blockIdx.x, t = threadIdx.x;
    if (bid < 3125) {
        int i = bid * 256 + t;
        if (i < 800000) {
            const float4* p = (const float4*)(x + (size_t)i * 8);
            float4 f0 = p[0], f1 = p[1];
            uint4 r;
            r.x = ((unsigned)f2bfu(f0.y) << 16) | f2bfu(f0.x);
            r.y = ((unsigned)f2bfu(f0.w) << 16) | f2bfu(f0.z);
            r.z = ((unsigned)f2bfu(f1.y) << 16) | f2bfu(f1.x);
            r.w = ((unsigned)f2bfu(f1.w) << 16) | f2bfu(f1.z);
            xb[i] = r;
        }
    } else if (bid < 3381) {
        int lb = bid - 3125;
        int layer = lb >> 7;
        int o = lb & 127;
        int k = t;  // 0..255
        const float* Wu = layer ? Wu2 : Wu1;
        const float* Wm = layer ? Wm2 : Wm1;
        const float* bm = layer ? bm2 : bm1;
        short* Wcatf = layer ? Wcatf2 : Wcatf1;
        float* cvec = layer ? c2 : c1;
        float val;
        if (k < 128) {
            val = Wu[o * 256 + k];
        } else {
            int kk = k - 128;
            float s = 0.f;
            for (int j = 0; j < 128; ++j) s += Wu[o * 256 + 128 + j] * Wm[j * 128 + kk];
            val = s;
        }
        Wcatf[(((k >> 3) * 128) + o) * 8 + (k & 7)] = f2bf(val);
        if (k == 0) {
            float cs = 0.f;
            for (int j = 0; j < 128; ++j) cs += Wu[o * 256 + 128 + j] * bm[j];
            cvec[o] = cs;
        }
    } else {
        int i = (bid - 3381) * 256 + t;
        if (i < 512 + 8192) zbase[i] = 0;
    }
}

// ---- bucket-sorted CSR build: bucket = row>>7 (128 rows per bucket) ----
__global__ __launch_bounds__(1024) void binhist_kernel(const int* __restrict__ row,
                                                       int* __restrict__ bhist, int E) {
    __shared__ int lh[NBUCK];
    int t = threadIdx.x;
    for (int i = t; i < NBUCK; i += 1024) lh[i] = 0;
    __syncthreads();
    int e0 = blockIdx.x * 4096;
#pragma unroll
    for (int k = 0; k < 4; ++k) {
        int e = e0 + k * 1024 + t;
        if (e < E) atomicAdd(&lh[row[e] >> 7], 1);
    }
    __syncthreads();
    for (int i = t; i < NBUCK; i += 1024)
        if (lh[i]) atomicAdd(&bhist[i], lh[i]);
}

// exclusive scan of bhist -> bbase[0..NBUCK], bcur=base
__global__ void bscan_kernel(const int* __restrict__ bhist, int* __restrict__ bbase,
                             int* __restrict__ bcur) {
    __shared__ int s[512];
    int t = threadIdx.x;
    int v = (t < NBUCK) ? bhist[t] : 0;
    s[t] = v;
    __syncthreads();
    for (int o = 1; o < 512; o <<= 1) {
        int a = (t >= o) ? s[t - o] : 0;
        __syncthreads();
        s[t] += a;
        __syncthreads();
    }
    if (t <= NBUCK) bbase[t] = s[t] - ((t < NBUCK) ? bhist[t] : 0);
    if (t < NBUCK) bcur[t] = s[t] - bhist[t];
}

// pass A: bin edges by bucket through LDS; write packed (row<<16|col) runs contiguously
__global__ __launch_bounds__(1024) void binA_kernel(const int* __restrict__ row,
                                                    const int* __restrict__ col,
                                                    int* __restrict__ bcur,
                                                    unsigned* __restrict__ ebin, int E) {
    __shared__ int lcur[NBUCK];
    __shared__ int lscan[NBUCK];
    __shared__ int gbase[NBUCK];
    __shared__ int sscan[512];
    __shared__ unsigned stage[4096];
    int t = threadIdx.x;
    for (int i = t; i < NBUCK; i += 1024) lcur[i] = 0;
    __syncthreads();
    int e0 = blockIdx.x * 4096;
    unsigned pv[4];
    int pb[4], pr[4];
#pragma unroll
    for (int k = 0; k < 4; ++k) {
        int e = e0 + k * 1024 + t;
        if (e < E) {
            int r = row[e], c = col[e];
            pv[k] = ((unsigned)r << 16) | (unsigned)c;
            pb[k] = r >> 7;
            pr[k] = atomicAdd(&lcur[pb[k]], 1);
        } else {
            pb[k] = -1;
        }
    }
    __syncthreads();
    if (t < 512) sscan[t] = (t < NBUCK) ? lcur[t] : 0;
    __syncthreads();
    for (int o = 1; o < 512; o <<= 1) {
        int a = 0;
        if (t < 512 && t >= o) a = sscan[t - o];
        __syncthreads();
        if (t < 512) sscan[t] += a;
        __syncthreads();
    }
    if (t < NBUCK) lscan[t] = sscan[t] - lcur[t];
    __syncthreads();
    for (int i = t; i < NBUCK; i += 1024) {
        int c = lcur[i];
        gbase[i] = c ? atomicAdd(&bcur[i], c) : 0;
    }
#pragma unroll
    for (int k = 0; k < 4; ++k)
        if (pb[k] >= 0) stage[lscan[pb[k]] + pr[k]] = pv[k];
    __syncthreads();
    int total = E - e0;
    if (total > 4096) total = 4096;
    for (int idx = t; idx < total; idx += 1024) {
        unsigned v = stage[idx];
        int b = v >> 23;
        ebin[gbase[b] + (idx - lscan[b])] = v;
    }
}

// pass B: per bucket, build csr segment + hist + off entirely in LDS, write coalesced
__global__ __launch_bounds__(256) void binB_kernel(const unsigned* __restrict__ ebin,
                                                   const int* __restrict__ bbase,
                                                   const int* __restrict__ bcur,
                                                   int* __restrict__ csr,
                                                   int* __restrict__ hist,
                                                   int* __restrict__ off, int N) {
    __shared__ int lcnt[128];
    __shared__ int loff[128];
    __shared__ int lcur2[128];
    __shared__ int sscan[128];
    __shared__ unsigned short stage[4096];
    int b = blockIdx.x, t = threadIdx.x;
    int base = bbase[b];
    int n = bcur[b] - base;
    if (n > 4096) n = 4096;  // safety clamp (cannot occur for this input)
    if (t < 128) lcnt[t] = 0;
    __syncthreads();
    for (int idx = t; idx < n; idx += 256) {
        unsigned v = ebin[base + idx];
        atomicAdd(&lcnt[(v >> 16) & 127], 1);
    }
    __syncthreads();
    if (t < 128) sscan[t] = lcnt[t];
    __syncthreads();
    for (int o = 1; o < 128; o <<= 1) {
        int a = 0;
        if (t < 128 && t >= o) a = sscan[t - o];
        __syncthreads();
        if (t < 128) sscan[t] += a;
        __syncthreads();
    }
    if (t < 128) {
        loff[t] = sscan[t] - lcnt[t];
        lcur2[t] = sscan[t] - lcnt[t];
    }
    __syncthreads();
    for (int idx = t; idx < n; idx += 256) {
        unsigned v = ebin[base + idx];
        int lr = (v >> 16) & 127;
        int pos = atomicAdd(&lcur2[lr], 1);
        stage[pos] = (unsigned short)(v & 0xffffu);
    }
    __syncthreads();
    for (int idx = t; idx < n; idx += 256) csr[base + idx] = (int)stage[idx];
    int r0 = b * 128;
    if (t < 128 && r0 + t < N) {
        hist[r0 + t] = lcnt[t];
        off[r0 + t] = base + loff[t];
    }
}

// agg[n] = sum of src rows (bf16) over csr neighbors. One wave per node.
// 16-lane group strides its own neighbors; group lanes share one csr[i] (HW broadcast).
__global__ __launch_bounds__(256) void gather_kernel(const unsigned short* __restrict__ src,
                                                     const int* __restrict__ off,
                                                     const int* __restrict__ hist,
                                                     const int* __restrict__ csr,
                                                     unsigned int* __restrict__ aggb, int N) {
    int wave = threadIdx.x >> 6, lane = threadIdx.x & 63;
    int n = blockIdx.x * 4 + wave;
    if (n >= N) return;
    int s = off[n];
    int e = s + hist[n];
    int grp = lane >> 4, sub = lane & 15;
    float a0 = 0.f, a1 = 0.f, a2 = 0.f, a3 = 0.f, a4 = 0.f, a5 = 0.f, a6 = 0.f, a7 = 0.f;
#pragma unroll 4
    for (int i = s + grp; i < e; i += 4) {
        int c = csr[i];
        uint4 v = *(const uint4*)(src + (size_t)c * 128 + sub * 8);
        a0 += bflo(v.x); a1 += bfhi(v.x);
        a2 += bflo(v.y); a3 += bfhi(v.y);
        a4 += bflo(v.z); a5 += bfhi(v.z);
        a6 += bflo(v.w); a7 += bfhi(v.w);
    }
#pragma unroll
    for (int mk = 16; mk <= 32; mk <<= 1) {
        a0 += __shfl_xor(a0, mk); a1 += __shfl_xor(a1, mk);
        a2 += __shfl_xor(a2, mk); a3 += __shfl_xor(a3, mk);
        a4 += __shfl_xor(a4, mk); a5 += __shfl_xor(a5, mk);
        a6 += __shfl_xor(a6, mk); a7 += __shfl_xor(a7, mk);
    }
    if (grp == 0) {
        uint4 r;
        r.x = ((unsigned)f2bfu(a1) << 16) | f2bfu(a0);
        r.y = ((unsigned)f2bfu(a3) << 16) | f2bfu(a2);
        r.z = ((unsigned)f2bfu(a5) << 16) | f2bfu(a4);
        r.w = ((unsigned)f2bfu(a7) << 16) | f2bfu(a6);
        ((uint4*)aggb)[(size_t)n * 16 + sub] = r;
    }
}

// h = relu([xin|agg] @ Wcat^T + deg*c + bu).  512 thr = 8 waves; block = 256 nodes.
template <int POOL>
__global__ __launch_bounds__(512) void update_kernel(
    const void* __restrict__ xin_, const unsigned int* __restrict__ aggb,
    const int* __restrict__ hist, const float* __restrict__ cvec,
    const float* __restrict__ bupd, const short* __restrict__ Wcatf,
    unsigned int* __restrict__ houtb, float* __restrict__ pooled,
    const int* __restrict__ batch, int N) {
    __shared__ short lds_s[32768];  // 64KB
    const int tid = threadIdx.x;
    const int wave = tid >> 6, lane = tid & 63;
    const int l31 = lane & 31, hi = lane >> 5;

    {  // stage B: linear 64KB copy
        const uint4* g = (const uint4*)Wcatf;
        uint4* l4 = (uint4*)lds_s;
#pragma unroll
        for (int j = 0; j < 8; ++j) l4[j * 512 + tid] = g[j * 512 + tid];
    }
    __syncthreads();

    const int m0 = blockIdx.x * 256 + wave * 32;
    int nr = m0 + l31;
    if (nr >= N) nr = N - 1;
    f32x16 acc[4] = {};
#pragma unroll
    for (int step = 0; step < 16; ++step) {
        short8 a;
        if (step < 8) {
            a = *(const short8*)((const short*)xin_ + (size_t)nr * 128 + step * 16 + hi * 8);
        } else {
            a = *(const short8*)((const short*)aggb + (size_t)nr * 128 + (step - 8) * 16 + hi * 8);
        }
#pragma unroll
        for (int ct = 0; ct < 4; ++ct) {
            const short8 b = *(const short8*)(lds_s + (((step * 2 + hi) * 128) + ct * 32 + l31) * 8);
            acc[ct] = __builtin_amdgcn_mfma_f32_32x32x16_bf16(a, b, acc[ct], 0, 0, 0);
        }
    }
    __syncthreads();  // B dead; LDS becomes transpose buffer

    float dv[16];
#pragma unroll
    for (int r = 0; r < 16; ++r) {
        int row = (r & 3) + 8 * (r >> 2) + 4 * hi;
        int node = m0 + row;
        if (node >= N) node = N - 1;
        dv[r] = (float)hist[node];
    }
    short* tp = lds_s + wave * 4096;  // [32][128] bf16 per wave
#pragma unroll
    for (int ct = 0; ct < 4; ++ct) {
        int o = ct * 32 + l31;
        float co = cvec[o], bo = bupd[o];
#pragma unroll
        for (int r = 0; r < 16; ++r) {
            int row = (r & 3) + 8 * (r >> 2) + 4 * hi;
            float v = fmaxf(acc[ct][r] + dv[r] * co + bo, 0.f);
            tp[row * 128 + o] = f2bf(v);
        }
    }
    __syncthreads();

    if (POOL == 0) {
        const uint4* l4 = (const uint4*)tp;
#pragma unroll
        for (int j = 0; j < 8; ++j) {
            int node = m0 + j * 4 + (lane >> 4);
            if (node < N)
                ((uint4*)houtb)[(size_t)m0 * 16 + j * 64 + lane] = l4[j * 64 + lane];
        }
    } else {
        // block-local segmented pool over sorted batch
        int c = tid & 127, seg = tid >> 7;
        int base = blockIdx.x * 256 + seg * 64;
        float s = 0.f;
        int gprev = -1;
        for (int i = 0; i < 64; ++i) {
            int node = base + i;
            if (node >= N) break;
            int g = batch[node];
            if (g != gprev) {
                if (gprev >= 0) atomicAdd(&pooled[gprev * 128 + c], s);
                s = 0.f;
                gprev = g;
            }
            unsigned u = (unsigned short)lds_s[(seg * 64 + i) * 128 + c];
            s += __uint_as_float(u << 16);
        }
        if (gprev >= 0) atomicAdd(&pooled[gprev * 128 + c], s);
    }
}

// out[g] = (pooled[g]/count(g)) @ Wcls^T + bcls; count via binary search on sorted batch
__global__ void final_kernel(const float* __restrict__ pooled, const int* __restrict__ batch,
                             const float* __restrict__ Wcls, const float* __restrict__ bcls,
                             float* __restrict__ out, int N) {
    __shared__ float sh[128];
    __shared__ int cntsh;
    int g = blockIdx.x;
    int t = threadIdx.x;
    if (t == 0) {
        int lo = 0, hi = N;
        while (lo < hi) { int mid = (lo + hi) >> 1; if (batch[mid] < g) lo = mid + 1; else hi = mid; }
        int start = lo;
        lo = 0; hi = N;
        while (lo < hi) { int mid = (lo + hi) >> 1; if (batch[mid] < g + 1) lo = mid + 1; else hi = mid; }
        cntsh = lo - start;
    }
    __syncthreads();
    float c = (cntsh > 0) ? (float)cntsh : 1.f;
    sh[t] = pooled[g * 128 + t] / c;
    __syncthreads();
    if (t < 10) {
        float s = bcls[t];
        for (int i = 0; i < 128; ++i) s += sh[i] * Wcls[t * 128 + i];
        out[g * 10 + t] = s;
    }
}

extern "C" void kernel_launch(void* const* d_in, const int* in_sizes, int n_in,
                              void* d_out, int out_size, void* d_ws, size_t ws_size,
                              hipStream_t stream) {
    const float* x = (const float*)d_in[0];
    const int* ei = (const int*)d_in[1];
    const int* batch = (const int*)d_in[2];
    const float* Wm1 = (const float*)d_in[3];
    const float* bm1 = (const float*)d_in[4];
    const float* Wu1 = (const float*)d_in[5];
    const float* bu1 = (const float*)d_in[6];
    const float* Wm2 = (const float*)d_in[7];
    const float* bm2 = (const float*)d_in[8];
    const float* Wu2 = (const float*)d_in[9];
    const float* bu2 = (const float*)d_in[10];
    const float* Wcls = (const float*)d_in[11];
    const float* bcls = (const float*)d_in[12];
    float* out = (float*)d_out;

    const int N = N_NODES, E = N_EDGES;
    const int* row = ei;
    const int* col = ei + E;
    const int EB = (E + 4095) / 4096;  // 196 binning blocks
    const int UB = (N + 255) / 256;    // 196 update blocks

    // workspace layout (int units from base); bhist+pooled contiguous for fused zeroing
    int* bhist = (int*)d_ws;                     // 512
    float* pooled = (float*)(bhist + 512);       // 8192
    int* bbase = (int*)(pooled + 8192);          // 512 (needs NBUCK+1)
    int* bcur = bbase + 512;                     // 512
    int* hist = bcur + 512;                      // 50000
    int* off = hist + 50000;                     // 50000
    unsigned* ebin = (unsigned*)(off + 50000);   // 800000
    int* csr = (int*)(ebin + 800000);            // 800000
    unsigned* aggb = (unsigned*)(csr + 800000);  // 3,200,000
    unsigned* h1b = aggb + 3200000;              // 3,200,000
    unsigned* xb = h1b + 3200000;                // 3,200,000
    float* c1 = (float*)(xb + 3200000);          // 128
    float* c2 = c1 + 128;                        // 128
    short* Wcatf1 = (short*)(c2 + 128);          // 32768 shorts
    short* Wcatf2 = Wcatf1 + 32768;              // 32768 shorts

    prep_kernel<<<3415, 256, 0, stream>>>(x, (uint4*)xb, Wu1, Wm1, bm1, Wcatf1, c1,
                                          Wu2, Wm2, bm2, Wcatf2, c2, bhist);
    binhist_kernel<<<EB, 1024, 0, stream>>>(row, bhist, E);
    bscan_kernel<<<1, 512, 0, stream>>>(bhist, bbase, bcur);
    binA_kernel<<<EB, 1024, 0, stream>>>(row, col, bcur, ebin, E);
    binB_kernel<<<NBUCK, 256, 0, stream>>>(ebin, bbase, bcur, csr, hist, off, N);

    // layer 1
    gather_kernel<<<(N + 3) / 4, 256, 0, stream>>>((const unsigned short*)xb, off, hist,
                                                   csr, aggb, N);
    update_kernel<0><<<UB, 512, 0, stream>>>(xb, aggb, hist, c1, bu1, Wcatf1,
                                             h1b, nullptr, nullptr, N);
    // layer 2
    gather_kernel<<<(N + 3) / 4, 256, 0, stream>>>((const unsigned short*)h1b, off, hist,
                                                   csr, aggb, N);
    update_kernel<1><<<UB, 512, 0, stream>>>(h1b, aggb, hist, c2, bu2, Wcatf2,
                                             nullptr, pooled, batch, N);

    final_kernel<<<NUM_GRAPHS, 128, 0, stream>>>(pooled, batch, Wcls, bcls, out, N);
}

// Round 7
// 135.399 us; speedup vs baseline: 12.3091x; 1.0625x over previous
//
#include <hip/hip_runtime.h>
#include <hip/hip_bf16.h>

#define N_NODES 50000
#define N_EDGES 800000
#define NUM_GRAPHS 64
#define NBUCK 391       // ceil(50000/128)
#define SLAB 4096       // slab capacity per bucket (expected ~2048)

typedef __attribute__((ext_vector_type(8))) short short8;
typedef __attribute__((ext_vector_type(16))) float f32x16;

static __device__ __forceinline__ short f2bf(float f) {
    union { __hip_bfloat16 h; short s; } u;
    u.h = __float2bfloat16(f);
    return u.s;
}
static __device__ __forceinline__ unsigned short f2bfu(float f) {
    union { __hip_bfloat16 h; unsigned short s; } u;
    u.h = __float2bfloat16(f);
    return u.s;
}
static __device__ __forceinline__ float bflo(unsigned u) { return __uint_as_float(u << 16); }
static __device__ __forceinline__ float bfhi(unsigned u) { return __uint_as_float(u & 0xffff0000u); }

// Fused: x->bf16 convert (blocks 0..3124) | weight folds (3125..3380)
//        | init bcur slab cursors + zero pooled (3381..3414)
__global__ __launch_bounds__(256) void prep_kernel(
    const float* __restrict__ x, uint4* __restrict__ xb,
    const float* __restrict__ Wu1, const float* __restrict__ Wm1,
    const float* __restrict__ bm1, short* __restrict__ Wcatf1, float* __restrict__ c1,
    const float* __restrict__ Wu2, const float* __restrict__ Wm2,
    const float* __restrict__ bm2, short* __restrict__ Wcatf2, float* __restrict__ c2,
    int* __restrict__ bcur, float* __restrict__ pooled) {
    int bid = blockIdx.x, t = threadIdx.x;
    if (bid < 3125) {
        int i = bid * 256 + t;
        if (i < 800000) {
            const float4* p = (const float4*)(x + (size_t)i * 8);
            float4 f0 = p[0], f1 = p[1];
            uint4 r;
            r.x = ((unsigned)f2bfu(f0.y) << 16) | f2bfu(f0.x);
            r.y = ((unsigned)f2bfu(f0.w) << 16) | f2bfu(f0.z);
            r.z = ((unsigned)f2bfu(f1.y) << 16) | f2bfu(f1.x);
            r.w = ((unsigned)f2bfu(f1.w) << 16) | f2bfu(f1.z);
            xb[i] = r;
        }
    } else if (bid < 3381) {
        int lb = bid - 3125;
        int layer = lb >> 7;
        int o = lb & 127;
        int k = t;  // 0..255
        const float* Wu = layer ? Wu2 : Wu1;
        const float* Wm = layer ? Wm2 : Wm1;
        const float* bm = layer ? bm2 : bm1;
        short* Wcatf = layer ? Wcatf2 : Wcatf1;
        float* cvec = layer ? c2 : c1;
        float val;
        if (k < 128) {
            val = Wu[o * 256 + k];
        } else {
            int kk = k - 128;
            float s = 0.f;
            for (int j = 0; j < 128; ++j) s += Wu[o * 256 + 128 + j] * Wm[j * 128 + kk];
            val = s;
        }
        Wcatf[(((k >> 3) * 128) + o) * 8 + (k & 7)] = f2bf(val);
        if (k == 0) {
            float cs = 0.f;
            for (int j = 0; j < 128; ++j) cs += Wu[o * 256 + 128 + j] * bm[j];
            cvec[o] = cs;
        }
    } else {
        int i = (bid - 3381) * 256 + t;
        if (i < 512) bcur[i] = i * SLAB;            // slab cursor = slab base
        else if (i < 512 + 8192) pooled[i - 512] = 0.f;
    }
}

// pass A: bin edges by bucket through LDS; slab-allocate runs via bcur atomics
__global__ __launch_bounds__(1024) void binA_kernel(const int* __restrict__ row,
                                                    const int* __restrict__ col,
                                                    int* __restrict__ bcur,
                                                    unsigned* __restrict__ ebin, int E) {
    __shared__ int lcur[NBUCK];
    __shared__ int lscan[NBUCK];
    __shared__ int gbase[NBUCK];
    __shared__ int sscan[512];
    __shared__ unsigned stage[4096];
    int t = threadIdx.x;
    for (int i = t; i < NBUCK; i += 1024) lcur[i] = 0;
    __syncthreads();
    int e0 = blockIdx.x * 4096;
    unsigned pv[4];
    int pb[4], pr[4];
#pragma unroll
    for (int k = 0; k < 4; ++k) {
        int e = e0 + k * 1024 + t;
        if (e < E) {
            int r = row[e], c = col[e];
            pv[k] = ((unsigned)r << 16) | (unsigned)c;
            pb[k] = r >> 7;
            pr[k] = atomicAdd(&lcur[pb[k]], 1);
        } else {
            pb[k] = -1;
        }
    }
    __syncthreads();
    if (t < 512) sscan[t] = (t < NBUCK) ? lcur[t] : 0;
    __syncthreads();
    for (int o = 1; o < 512; o <<= 1) {
        int a = 0;
        if (t < 512 && t >= o) a = sscan[t - o];
        __syncthreads();
        if (t < 512) sscan[t] += a;
        __syncthreads();
    }
    if (t < NBUCK) lscan[t] = sscan[t] - lcur[t];
    __syncthreads();
    for (int i = t; i < NBUCK; i += 1024) {
        int c = lcur[i];
        gbase[i] = c ? atomicAdd(&bcur[i], c) : 0;
    }
#pragma unroll
    for (int k = 0; k < 4; ++k)
        if (pb[k] >= 0) stage[lscan[pb[k]] + pr[k]] = pv[k];
    __syncthreads();
    int total = E - e0;
    if (total > 4096) total = 4096;
    for (int idx = t; idx < total; idx += 1024) {
        unsigned v = stage[idx];
        int b = v >> 23;
        ebin[gbase[b] + (idx - lscan[b])] = v;
    }
}

// pass B: per bucket slab, build csr segment + hist + off entirely in LDS
__global__ __launch_bounds__(256) void binB_kernel(const unsigned* __restrict__ ebin,
                                                   const int* __restrict__ bcur,
                                                   int* __restrict__ csr,
                                                   int* __restrict__ hist,
                                                   int* __restrict__ off, int N) {
    __shared__ int lcnt[128];
    __shared__ int loff[128];
    __shared__ int lcur2[128];
    __shared__ int sscan[128];
    __shared__ unsigned short stage[SLAB];
    int b = blockIdx.x, t = threadIdx.x;
    int base = b * SLAB;
    int n = bcur[b] - base;
    if (n > SLAB) n = SLAB;  // safety clamp
    if (t < 128) lcnt[t] = 0;
    __syncthreads();
    for (int idx = t; idx < n; idx += 256) {
        unsigned v = ebin[base + idx];
        atomicAdd(&lcnt[(v >> 16) & 127], 1);
    }
    __syncthreads();
    if (t < 128) sscan[t] = lcnt[t];
    __syncthreads();
    for (int o = 1; o < 128; o <<= 1) {
        int a = 0;
        if (t < 128 && t >= o) a = sscan[t - o];
        __syncthreads();
        if (t < 128) sscan[t] += a;
        __syncthreads();
    }
    if (t < 128) {
        loff[t] = sscan[t] - lcnt[t];
        lcur2[t] = sscan[t] - lcnt[t];
    }
    __syncthreads();
    for (int idx = t; idx < n; idx += 256) {
        unsigned v = ebin[base + idx];
        int lr = (v >> 16) & 127;
        int pos = atomicAdd(&lcur2[lr], 1);
        stage[pos] = (unsigned short)(v & 0xffffu);
    }
    __syncthreads();
    for (int idx = t; idx < n; idx += 256) csr[base + idx] = (int)stage[idx];
    int r0 = b * 128;
    if (t < 128 && r0 + t < N) {
        hist[r0 + t] = lcnt[t];
        off[r0 + t] = base + loff[t];
    }
}

// agg[n] = sum of src rows (bf16) over csr neighbors. One wave per node.
// 16-lane group strides its own neighbors; group lanes share one csr[i] (HW broadcast).
__global__ __launch_bounds__(256) void gather_kernel(const unsigned short* __restrict__ src,
                                                     const int* __restrict__ off,
                                                     const int* __restrict__ hist,
                                                     const int* __restrict__ csr,
                                                     unsigned int* __restrict__ aggb, int N) {
    int wave = threadIdx.x >> 6, lane = threadIdx.x & 63;
    int n = blockIdx.x * 4 + wave;
    if (n >= N) return;
    int s = off[n];
    int e = s + hist[n];
    int grp = lane >> 4, sub = lane & 15;
    float a0 = 0.f, a1 = 0.f, a2 = 0.f, a3 = 0.f, a4 = 0.f, a5 = 0.f, a6 = 0.f, a7 = 0.f;
#pragma unroll 4
    for (int i = s + grp; i < e; i += 4) {
        int c = csr[i];
        uint4 v = *(const uint4*)(src + (size_t)c * 128 + sub * 8);
        a0 += bflo(v.x); a1 += bfhi(v.x);
        a2 += bflo(v.y); a3 += bfhi(v.y);
        a4 += bflo(v.z); a5 += bfhi(v.z);
        a6 += bflo(v.w); a7 += bfhi(v.w);
    }
#pragma unroll
    for (int mk = 16; mk <= 32; mk <<= 1) {
        a0 += __shfl_xor(a0, mk); a1 += __shfl_xor(a1, mk);
        a2 += __shfl_xor(a2, mk); a3 += __shfl_xor(a3, mk);
        a4 += __shfl_xor(a4, mk); a5 += __shfl_xor(a5, mk);
        a6 += __shfl_xor(a6, mk); a7 += __shfl_xor(a7, mk);
    }
    if (grp == 0) {
        uint4 r;
        r.x = ((unsigned)f2bfu(a1) << 16) | f2bfu(a0);
        r.y = ((unsigned)f2bfu(a3) << 16) | f2bfu(a2);
        r.z = ((unsigned)f2bfu(a5) << 16) | f2bfu(a4);
        r.w = ((unsigned)f2bfu(a7) << 16) | f2bfu(a6);
        ((uint4*)aggb)[(size_t)n * 16 + sub] = r;
    }
}

// h = relu([xin|agg] @ Wcat^T + deg*c + bu).  512 thr = 8 waves; block = 256 nodes.
template <int POOL>
__global__ __launch_bounds__(512) void update_kernel(
    const void* __restrict__ xin_, const unsigned int* __restrict__ aggb,
    const int* __restrict__ hist, const float* __restrict__ cvec,
    const float* __restrict__ bupd, const short* __restrict__ Wcatf,
    unsigned int* __restrict__ houtb, float* __restrict__ pooled,
    const int* __restrict__ batch, int N) {
    __shared__ short lds_s[32768];  // 64KB
    const int tid = threadIdx.x;
    const int wave = tid >> 6, lane = tid & 63;
    const int l31 = lane & 31, hi = lane >> 5;

    {  // stage B: linear 64KB copy
        const uint4* g = (const uint4*)Wcatf;
        uint4* l4 = (uint4*)lds_s;
#pragma unroll
        for (int j = 0; j < 8; ++j) l4[j * 512 + tid] = g[j * 512 + tid];
    }
    __syncthreads();

    const int m0 = blockIdx.x * 256 + wave * 32;
    int nr = m0 + l31;
    if (nr >= N) nr = N - 1;
    f32x16 acc[4] = {};
#pragma unroll
    for (int step = 0; step < 16; ++step) {
        short8 a;
        if (step < 8) {
            a = *(const short8*)((const short*)xin_ + (size_t)nr * 128 + step * 16 + hi * 8);
        } else {
            a = *(const short8*)((const short*)aggb + (size_t)nr * 128 + (step - 8) * 16 + hi * 8);
        }
#pragma unroll
        for (int ct = 0; ct < 4; ++ct) {
            const short8 b = *(const short8*)(lds_s + (((step * 2 + hi) * 128) + ct * 32 + l31) * 8);
            acc[ct] = __builtin_amdgcn_mfma_f32_32x32x16_bf16(a, b, acc[ct], 0, 0, 0);
        }
    }
    __syncthreads();  // B dead; LDS becomes transpose buffer

    float dv[16];
#pragma unroll
    for (int r = 0; r < 16; ++r) {
        int row = (r & 3) + 8 * (r >> 2) + 4 * hi;
        int node = m0 + row;
        if (node >= N) node = N - 1;
        dv[r] = (float)hist[node];
    }
    short* tp = lds_s + wave * 4096;  // [32][128] bf16 per wave
#pragma unroll
    for (int ct = 0; ct < 4; ++ct) {
        int o = ct * 32 + l31;
        float co = cvec[o], bo = bupd[o];
#pragma unroll
        for (int r = 0; r < 16; ++r) {
            int row = (r & 3) + 8 * (r >> 2) + 4 * hi;
            float v = fmaxf(acc[ct][r] + dv[r] * co + bo, 0.f);
            tp[row * 128 + o] = f2bf(v);
        }
    }
    __syncthreads();

    if (POOL == 0) {
        const uint4* l4 = (const uint4*)tp;
#pragma unroll
        for (int j = 0; j < 8; ++j) {
            int node = m0 + j * 4 + (lane >> 4);
            if (node < N)
                ((uint4*)houtb)[(size_t)m0 * 16 + j * 64 + lane] = l4[j * 64 + lane];
        }
    } else {
        // block-local segmented pool over sorted batch
        int c = tid & 127, seg = tid >> 7;
        int base = blockIdx.x * 256 + seg * 64;
        float s = 0.f;
        int gprev = -1;
        for (int i = 0; i < 64; ++i) {
            int node = base + i;
            if (node >= N) break;
            int g = batch[node];
            if (g != gprev) {
                if (gprev >= 0) atomicAdd(&pooled[gprev * 128 + c], s);
                s = 0.f;
                gprev = g;
            }
            unsigned u = (unsigned short)lds_s[(seg * 64 + i) * 128 + c];
            s += __uint_as_float(u << 16);
        }
        if (gprev >= 0) atomicAdd(&pooled[gprev * 128 + c], s);
    }
}

// out[g] = (pooled[g]/count(g)) @ Wcls^T + bcls; count via binary search on sorted batch
__global__ void final_kernel(const float* __restrict__ pooled, const int* __restrict__ batch,
                             const float* __restrict__ Wcls, const float* __restrict__ bcls,
                             float* __restrict__ out, int N) {
    __shared__ float sh[128];
    __shared__ int cntsh;
    int g = blockIdx.x;
    int t = threadIdx.x;
    if (t == 0) {
        int lo = 0, hi = N;
        while (lo < hi) { int mid = (lo + hi) >> 1; if (batch[mid] < g) lo = mid + 1; else hi = mid; }
        int start = lo;
        lo = 0; hi = N;
        while (lo < hi) { int mid = (lo + hi) >> 1; if (batch[mid] < g + 1) lo = mid + 1; else hi = mid; }
        cntsh = lo - start;
    }
    __syncthreads();
    float c = (cntsh > 0) ? (float)cntsh : 1.f;
    sh[t] = pooled[g * 128 + t] / c;
    __syncthreads();
    if (t < 10) {
        float s = bcls[t];
        for (int i = 0; i < 128; ++i) s += sh[i] * Wcls[t * 128 + i];
        out[g * 10 + t] = s;
    }
}

extern "C" void kernel_launch(void* const* d_in, const int* in_sizes, int n_in,
                              void* d_out, int out_size, void* d_ws, size_t ws_size,
                              hipStream_t stream) {
    const float* x = (const float*)d_in[0];
    const int* ei = (const int*)d_in[1];
    const int* batch = (const int*)d_in[2];
    const float* Wm1 = (const float*)d_in[3];
    const float* bm1 = (const float*)d_in[4];
    const float* Wu1 = (const float*)d_in[5];
    const float* bu1 = (const float*)d_in[6];
    const float* Wm2 = (const float*)d_in[7];
    const float* bm2 = (const float*)d_in[8];
    const float* Wu2 = (const float*)d_in[9];
    const float* bu2 = (const float*)d_in[10];
    const float* Wcls = (const float*)d_in[11];
    const float* bcls = (const float*)d_in[12];
    float* out = (float*)d_out;

    const int N = N_NODES, E = N_EDGES;
    const int* row = ei;
    const int* col = ei + E;
    const int EB = (E + 4095) / 4096;  // 196 binning blocks
    const int UB = (N + 255) / 256;    // 196 update blocks

    // workspace layout (int units from base)
    int* bcur = (int*)d_ws;                        // 512
    float* pooled = (float*)(bcur + 512);          // 8192
    int* hist = (int*)(pooled + 8192);             // 50000
    int* off = hist + 50000;                       // 50000
    unsigned* ebin = (unsigned*)(off + 50000);     // NBUCK*SLAB = 1,601,536
    int* csr = (int*)(ebin + NBUCK * SLAB);        // 1,601,536
    unsigned* aggb = (unsigned*)(csr + NBUCK * SLAB);  // 3,200,000
    unsigned* h1b = aggb + 3200000;                // 3,200,000
    unsigned* xb = h1b + 3200000;                  // 3,200,000
    float* c1 = (float*)(xb + 3200000);            // 128
    float* c2 = c1 + 128;                          // 128
    short* Wcatf1 = (short*)(c2 + 128);            // 32768 shorts
    short* Wcatf2 = Wcatf1 + 32768;                // 32768 shorts

    prep_kernel<<<3415, 256, 0, stream>>>(x, (uint4*)xb, Wu1, Wm1, bm1, Wcatf1, c1,
                                          Wu2, Wm2, bm2, Wcatf2, c2, bcur, pooled);
    binA_kernel<<<EB, 1024, 0, stream>>>(row, col, bcur, ebin, E);
    binB_kernel<<<NBUCK, 256, 0, stream>>>(ebin, bcur, csr, hist, off, N);

    // layer 1
    gather_kernel<<<(N + 3) / 4, 256, 0, stream>>>((const unsigned short*)xb, off, hist,
                                                   csr, aggb, N);
    update_kernel<0><<<UB, 512, 0, stream>>>(xb, aggb, hist, c1, bu1, Wcatf1,
                                             h1b, nullptr, nullptr, N);
    // layer 2
    gather_kernel<<<(N + 3) / 4, 256, 0, stream>>>((const unsigned short*)h1b, off, hist,
                                                   csr, aggb, N);
    update_kernel<1><<<UB, 512, 0, stream>>>(h1b, aggb, hist, c2, bu2, Wcatf2,
                                             nullptr, pooled, batch, N);

    final_kernel<<<NUM_GRAPHS, 128, 0, stream>>>(pooled, batch, Wcls, bcls, out, N);
}